// Round 15
// baseline (467.836 us; speedup 1.0000x reference)
//
#include <hip/hip_runtime.h>

typedef short bf16x8 __attribute__((ext_vector_type(8)));
typedef short bf16x4 __attribute__((ext_vector_type(4)));
typedef float f32x4 __attribute__((ext_vector_type(4)));

#define DEVI __device__ __forceinline__

constexpr int N   = 32768;
constexpr int C   = 128;
constexpr int E   = 524288;
constexpr float EPSV = 1e-5f;
constexpr int UT_BLOCKS = 256;   // each block covers 128 rows (4 chunks of 32)
constexpr int HB  = 128;         // histogram blocks per edge-array (src / dst)
constexpr int EPB = E / HB;      // 4096 edges per histogram block
// softmax scale folded into Q at QKV-GEMM epilogue: 1/sqrt(32) * log2(e)
constexpr float QSCALE = 0.17677669529663687f * 1.4426950408889634f;

DEVI float bf2f(ushort u){ return __uint_as_float(((uint)u) << 16); }
DEVI ushort f2bf(float f){
  uint u = __float_as_uint(f);
  return (ushort)((u + 0x7fffu + ((u >> 16) & 1u)) >> 16);
}
// packed f32 pair -> bf16 pair (round-to-nearest-even), single HW instr
DEVI uint cvtpk(float lo, float hi){
  uint r;
  asm("v_cvt_pk_bf16_f32 %0, %1, %2" : "=v"(r) : "v"(lo), "v"(hi));
  return r;
}
// single-instruction 2^x (no libm edge-case code)
DEVI float fexp2(float x){
  float r;
  asm("v_exp_f32 %0, %1" : "=v"(r) : "v"(x));
  return r;
}
DEVI float sane(float v){ if (!(v == v)) return 0.f; return fminf(fmaxf(v, -1e30f), 1e30f); }
DEVI bool mode_fp32(const uint* lmraw){ return (lmraw[0] & 0xffffu) == 0u; }

// ---------------- canonical small-input table ----------------
constexpr int CSZ[28] = {128,1,16384,128,16384,128,16384,128,16384,128,81920,128,
                         1,16384,49152,384,16384,128,32768,256,32768,128,
                         128,128,128,128,128,128};
constexpr int COF[28] = {0,128,192,16576,16704,33088,33216,49600,49728,66112,
                         66240,148160,148288,148352,164736,213888,214272,230656,
                         230784,263552,263808,296576,296704,296832,296960,297088,
                         297216,297344};
constexpr int CAN_SMALL_TOTAL = 297472;

// ---------------- weight pre-transpose layout ----------------
constexpr int WT_SPA1 = 0;
constexpr int WT_SPA2 = 16384;
constexpr int WT_SPE1 = 32768;
constexpr int WT_SPE2 = 49152;
constexpr int WT_PROJ = 65536;
constexpr int WT_CHEB = 81920;    // 128 x 640 (concat layout)
constexpr int WT_QKV  = 163840;   // 384 x 128
constexpr int WT_WOUT = 212992;
constexpr int WT_MLP1 = 229376;   // 256 x 128
constexpr int WT_MLP2 = 262144;   // 128 x 256
constexpr int WT_TOTAL = 294912;

struct CvtArgs { const void* src[28]; };

DEVI ushort cvt_elem(const void* p, int j, bool f32){
  return f32 ? f2bf(((const float*)p)[j]) : ((const ushort*)p)[j];
}

// ---------------- fused front-end: convert big/small + transpose + zero ----
__global__ __launch_bounds__(256) void prep_all(CvtArgs a,
    const void* __restrict__ xs, const void* __restrict__ Us,
    ushort* __restrict__ canx, ushort* __restrict__ canu,
    ushort* __restrict__ cs, ushort* __restrict__ wt,
    int* __restrict__ zp, const uint* __restrict__ lmraw)
{
  bool f32 = mode_fp32(lmraw);
  int b = blockIdx.x, tid = threadIdx.x;
  if (b < 8192) {
    size_t e = ((size_t)b * 256 + tid) * 4;
    bool isU = e >= (size_t)N * C;
    size_t off = isU ? e - (size_t)N * C : e;
    const void* src = isU ? Us : xs;
    ushort* dst = isU ? canu : canx;
    ushort4 o;
    if (f32) {
      float4 v = *(const float4*)((const float*)src + off);
      o.x = f2bf(v.x); o.y = f2bf(v.y); o.z = f2bf(v.z); o.w = f2bf(v.w);
    } else {
      o = *(const ushort4*)((const ushort*)src + off);
    }
    *(ushort4*)(dst + off) = o;
  } else if (b < 9354) {
    int idx = (b - 8192) * 256 + tid;
    #pragma unroll 1
    for (int s = 0; s < 28; s++) {
      if (idx < CSZ[s]) { cs[COF[s] + idx] = cvt_elem(a.src[s], idx, f32); return; }
      idx -= CSZ[s];
    }
  } else if (b < 10506) {
    int i = (b - 9354) * 256 + tid;
    if (i < 81920) {
      int m = i >> 14, r = i & 16383; int k = r >> 7, n = r & 127;
      const void* src = m==0?a.src[2] : m==1?a.src[4] : m==2?a.src[6] : m==3?a.src[8] : a.src[13];
      wt[m*16384 + n*128 + k] = cvt_elem(src, r, f32);
    } else if (i < 163840) {
      int j = i - 81920; int m = j >> 14, r = j & 16383; int k = r >> 7, n = r & 127;
      wt[WT_CHEB + n*640 + m*128 + k] = cvt_elem(a.src[10], j, f32);
    } else if (i < 212992) {
      int j = i - 163840; int k = j / 384, n = j % 384;
      wt[WT_QKV + n*128 + k] = cvt_elem(a.src[14], j, f32);
    } else if (i < 229376) {
      int j = i - 212992; int k = j >> 7, n = j & 127;
      wt[WT_WOUT + n*128 + k] = cvt_elem(a.src[16], j, f32);
    } else if (i < 262144) {
      int j = i - 229376; int k = j >> 8, n = j & 255;
      wt[WT_MLP1 + n*128 + k] = cvt_elem(a.src[18], j, f32);
    } else if (i < WT_TOTAL) {
      int j = i - 262144; int k = j >> 7, n = j & 127;
      wt[WT_MLP2 + n*256 + k] = cvt_elem(a.src[20], j, f32);
    }
  } else {
    int i = (b - 10506) * 256 + tid;
    if (i < 6144) zp[i] = 0;     // 3 BN x 8 replicas x 256 floats
  }
}

// ---------------- edge prep: LDS-private histograms (no device atomics) ----
__global__ __launch_bounds__(1024) void hist_lds(const int* __restrict__ ei,
    int* __restrict__ cei, ushort* __restrict__ part)
{
  __shared__ uint hist[N / 2];          // 64 KB, two bins per word
  int t = threadIdx.x;
  int b = blockIdx.x;
  bool i64 = ((ei[1] | ei[3] | ei[5] | ei[7]) == 0);
  size_t j0 = (size_t)b * EPB;
  #pragma unroll
  for (int i = t; i < N / 2; i += 1024) hist[i] = 0u;
  __syncthreads();
  for (int k = t; k < EPB; k += 1024) {
    size_t j = j0 + k;
    int v = (i64 ? ei[2 * j] : ei[j]) & (N - 1);
    cei[j] = v;
    atomicAdd(&hist[v >> 1], 1u << ((v & 1) * 16));
  }
  __syncthreads();
  uint* po = (uint*)(part + (size_t)b * N);
  for (int i = t; i < N / 2; i += 1024) po[i] = hist[i];
}

// fold partials: src totals -> dis, dst totals -> cdt
__global__ __launch_bounds__(256) void reduce_cnt(const ushort* __restrict__ part,
    int* __restrict__ cdt, float* __restrict__ dis)
{
  int d = blockIdx.x * 256 + threadIdx.x;
  int s = 0, tt = 0;
  #pragma unroll 8
  for (int b = 0; b < HB; b++) s  += part[(size_t)b * N + d];
  #pragma unroll 8
  for (int b = 0; b < HB; b++) tt += part[(size_t)(HB + b) * N + d];
  cdt[d] = tt;
  dis[d] = s > 0 ? rsqrtf((float)s) : 0.f;
}

__global__ __launch_bounds__(1024) void scan_kernel(const int* __restrict__ cnt,
                                                    int* __restrict__ row_ptr)
{
  __shared__ int sums[1024];
  int t = threadIdx.x;
  int loc[32]; int s = 0;
  int base = t * 32;
  #pragma unroll
  for (int i = 0; i < 32; i++) { loc[i] = s; s += cnt[base + i]; }
  sums[t] = s;
  __syncthreads();
  for (int off = 1; off < 1024; off <<= 1) {
    int v = (t >= off) ? sums[t - off] : 0;
    __syncthreads();
    sums[t] += v;
    __syncthreads();
  }
  int pre = (t == 0) ? 0 : sums[t - 1];
  #pragma unroll
  for (int i = 0; i < 32; i++) row_ptr[base + i] = pre + loc[i];
}

// per-hist-block slot bases: off2[b][d] = rp[d] + sum_{b'<b} partD[b'][d]
__global__ __launch_bounds__(256) void off_kernel(const int* __restrict__ rp,
    const ushort* __restrict__ part, int* __restrict__ off2)
{
  int d = blockIdx.x * 256 + threadIdx.x;
  int run = rp[d];
  #pragma unroll 8
  for (int b = 0; b < HB; b++) {
    off2[(size_t)b * N + d] = run;
    run += part[(size_t)(HB + b) * N + d];
  }
}

// deterministic scatter: block b replays its edge slice, ranks via LDS atomics
__global__ __launch_bounds__(1024) void edge_scatter(const int* __restrict__ cei,
    const int* __restrict__ off2, const float* __restrict__ dis,
    int2* __restrict__ ep)
{
  __shared__ int base[N];               // 128 KB slot cursors
  int t = threadIdx.x;
  int b = blockIdx.x;                   // 0..HB-1
  for (int i = t; i < N; i += 1024) base[i] = off2[(size_t)b * N + i];
  __syncthreads();
  size_t e0 = (size_t)b * EPB;
  for (int k = t; k < EPB; k += 1024) {
    size_t e = e0 + k;
    int s = cei[e], d = cei[e + E];
    int slot = atomicAdd(&base[d], 1);
    int2 v; v.x = s; v.y = __float_as_int(dis[s] * dis[d]);
    ep[slot] = v;
  }
}

// ---------------- LDS-staged MFMA GEMM (optional fused BN-stats) ----------
template<int K, int COLS, bool RELU, int OMODE, bool BIAS, bool RES, int ASTR, int OSTR, bool QSC, bool STATS>
__global__ __launch_bounds__(256) void gemm_lds(
    const ushort* __restrict__ A, const ushort* __restrict__ WT,
    const ushort* __restrict__ bias, const ushort* __restrict__ res,
    void* __restrict__ outp, float* __restrict__ gstats)
{
  constexpr int NSEG = COLS / 128;
  constexpr int NKC = K / 128;
  constexpr int BP = 136;
  __shared__ ushort Bs[128 * BP];
  __shared__ float ls[STATS ? 256 : 1];
  int tid = threadIdx.x;
  int lane = tid & 63, wave = tid >> 6;
  int quad = lane >> 4, l16 = lane & 15;
  int seg = (NSEG > 1) ? (blockIdx.x % NSEG) : 0;
  int rb  = (NSEG > 1) ? (blockIdx.x / NSEG) : blockIdx.x;
  int row0 = rb * 64 + wave * 16;
  const ushort* wseg = WT + (size_t)(seg * 128) * K;

  f32x4 acc[8];
  #pragma unroll
  for (int nt = 0; nt < 8; nt++) acc[nt] = (f32x4){0.f, 0.f, 0.f, 0.f};

  // preload kc=0 A fragments (overlaps HBM latency with staging below)
  bf16x8 a[4];
  {
    const ushort* ap = A + (size_t)(row0 + l16) * ASTR + quad * 8;
    #pragma unroll
    for (int kk = 0; kk < 4; kk++) a[kk] = *(const bf16x8*)(ap + kk * 32);
  }

  for (int kc = 0; kc < NKC; kc++) {
    if (kc) __syncthreads();
    #pragma unroll
    for (int i = tid; i < 2048; i += 256) {
      int col = i >> 4, ko = (i & 15) * 8;
      *(bf16x8*)&Bs[col * BP + ko] =
          *(const bf16x8*)(wseg + (size_t)col * K + kc * 128 + ko);
    }
    __syncthreads();
    if (kc) {
      const ushort* ap = A + (size_t)(row0 + l16) * ASTR + kc * 128 + quad * 8;
      #pragma unroll
      for (int kk = 0; kk < 4; kk++) a[kk] = *(const bf16x8*)(ap + kk * 32);
    }
    #pragma unroll
    for (int kk = 0; kk < 4; kk++) {
      #pragma unroll
      for (int nt = 0; nt < 8; nt++) {
        bf16x8 b = *(const bf16x8*)(&Bs[(nt * 16 + l16) * BP + kk * 32 + quad * 8]);
        acc[nt] = __builtin_amdgcn_mfma_f32_16x16x32_bf16(a[kk], b, acc[nt], 0, 0, 0);
      }
    }
  }

  if (STATS) {
    if (tid < 256) ls[tid] = 0.f;
    __syncthreads();
  }

  #pragma unroll
  for (int nt = 0; nt < 8; nt++) {
    int col = seg * 128 + nt * 16 + l16;
    float bv = 0.f;
    if (BIAS) bv = bf2f(bias[col]);
    float cs_ = 0.f, cs2 = 0.f;
    #pragma unroll
    for (int r = 0; r < 4; r++) {
      int row = row0 + quad * 4 + r;
      size_t oi = (size_t)row * OSTR + col;
      float v = acc[nt][r] + bv;
      if (RES) v += bf2f(res[(size_t)row * COLS + col]);
      if (RELU) v = fmaxf(v, 0.f);
      if (QSC && col < 128) v *= QSCALE;
      float nv;
      if (OMODE == 0)      { ((ushort*)outp)[oi] = f2bf(v); nv = v; }
      else if (OMODE == 1) { ((float*)outp)[oi] = v; nv = v; }
      else                 { float* fo = (float*)outp + oi; nv = *fo + v; *fo = nv; }
      if (STATS) { float sv = sane(nv); cs_ += sv; cs2 += sv * sv; }
    }
    if (STATS) { atomicAdd(&ls[col], cs_); atomicAdd(&ls[128 + col], cs2); }
  }

  if (STATS) {
    __syncthreads();
    float* gs = gstats + (blockIdx.x & 7) * 256;
    if (tid < 128) {
      atomicAdd(&gs[tid], ls[tid]);
      atomicAdd(&gs[128 + tid], ls[128 + tid]);
    }
  }
}

// ---------------- fused cheb+spectral GEMM (prefetch-all + dbuf) ----------
__global__ __launch_bounds__(256) void gemm_cheb_mt(
    const ushort* __restrict__ Tb, const ushort* __restrict__ Wc,
    const ushort* __restrict__ chebB,
    const ushort* __restrict__ canu, const ushort* __restrict__ MT,
    const ushort* __restrict__ canx,
    float* __restrict__ outp, float* __restrict__ gstats)
{
  constexpr int BP = 136;
  __shared__ ushort Bs[2][128 * BP];   // 69.6 KB double buffer
  __shared__ float ls[256];
  int tid = threadIdx.x;
  int lane = tid & 63, wave = tid >> 6;
  int quad = lane >> 4, l16 = lane & 15;
  int row0 = blockIdx.x * 64 + wave * 16;

  // prefetch ALL A fragments: 24 independent 16B loads
  bf16x8 a0[4], a1[4], a2[4], a3[4], a4[4], a5[4];
  {
    const ushort* tb = Tb   + (size_t)(row0 + l16) * 640 + quad * 8;
    const ushort* cu = canu + (size_t)(row0 + l16) * 128 + quad * 8;
    #pragma unroll
    for (int kk = 0; kk < 4; kk++) {
      a0[kk] = *(const bf16x8*)(tb + 0 * 128 + kk * 32);
      a1[kk] = *(const bf16x8*)(tb + 1 * 128 + kk * 32);
      a2[kk] = *(const bf16x8*)(tb + 2 * 128 + kk * 32);
      a3[kk] = *(const bf16x8*)(tb + 3 * 128 + kk * 32);
      a4[kk] = *(const bf16x8*)(tb + 4 * 128 + kk * 32);
      a5[kk] = *(const bf16x8*)(cu + kk * 32);
    }
  }

  f32x4 acc[8];
  #pragma unroll
  for (int nt = 0; nt < 8; nt++) acc[nt] = (f32x4){0.f, 0.f, 0.f, 0.f};

  // stage chunk 0 into buffer 0
  for (int i = tid; i < 2048; i += 256) {
    int col = i >> 4, ko = (i & 15) * 8;
    *(bf16x8*)&Bs[0][col * BP + ko] = *(const bf16x8*)(Wc + (size_t)col * 640 + ko);
  }
  __syncthreads();

  #pragma unroll
  for (int kc = 0; kc < 6; kc++) {
    int cur = kc & 1;
    if (kc + 1 < 6) {
      for (int i = tid; i < 2048; i += 256) {
        int col = i >> 4, ko = (i & 15) * 8;
        *(bf16x8*)&Bs[cur ^ 1][col * BP + ko] = (kc + 1 == 5)
            ? *(const bf16x8*)(MT + (size_t)col * 128 + ko)
            : *(const bf16x8*)(Wc + (size_t)col * 640 + (kc + 1) * 128 + ko);
      }
    }
    const bf16x8* av = kc == 0 ? a0 : kc == 1 ? a1 : kc == 2 ? a2
                     : kc == 3 ? a3 : kc == 4 ? a4 : a5;
    #pragma unroll
    for (int kk = 0; kk < 4; kk++)
      #pragma unroll
      for (int nt = 0; nt < 8; nt++) {
        bf16x8 b = *(const bf16x8*)(&Bs[cur][(nt * 16 + l16) * BP + kk * 32 + quad * 8]);
        acc[nt] = __builtin_amdgcn_mfma_f32_16x16x32_bf16(av[kk], b, acc[nt], 0, 0, 0);
      }
    __syncthreads();
  }

  if (tid < 256) ls[tid] = 0.f;
  __syncthreads();

  #pragma unroll
  for (int nt = 0; nt < 8; nt++) {
    int col = nt * 16 + l16;
    float bv = bf2f(chebB[col]);
    float cs_ = 0.f, cs2 = 0.f;
    #pragma unroll
    for (int r = 0; r < 4; r++) {
      int row = row0 + quad * 4 + r;
      float v = acc[nt][r] + bv + bf2f(canx[(size_t)row * 128 + col]);
      outp[(size_t)row * 128 + col] = v;
      float sv = sane(v); cs_ += sv; cs2 += sv * sv;
    }
    atomicAdd(&ls[col], cs_); atomicAdd(&ls[128 + col], cs2);
  }
  __syncthreads();
  float* gs = gstats + (blockIdx.x & 7) * 256;
  if (tid < 128) {
    atomicAdd(&gs[tid], ls[tid]);
    atomicAdd(&gs[128 + tid], ls[128 + tid]);
  }
}

// ---------------- QKV GEMM: one A-read, 3 segments, reg-prefetched --------
__global__ __launch_bounds__(256) void gemm_qkv(
    const ushort* __restrict__ A, const ushort* __restrict__ WT,
    const ushort* __restrict__ bias, ushort* __restrict__ outp)
{
  constexpr int BP = 136;
  __shared__ ushort Bs[128 * BP];
  int tid = threadIdx.x;
  int lane = tid & 63, wave = tid >> 6;
  int quad = lane >> 4, l16 = lane & 15;
  int row0 = blockIdx.x * 64 + wave * 16;
  bf16x8 a[4];
  {
    const ushort* ap = A + (size_t)(row0 + l16) * 128 + quad * 8;
    #pragma unroll
    for (int kk = 0; kk < 4; kk++) a[kk] = *(const bf16x8*)(ap + kk * 32);
  }

  bf16x8 wreg[8];
  auto loadW = [&](int segi){
    #pragma unroll
    for (int r = 0; r < 8; r++) {
      int i = tid + r * 256;
      wreg[r] = *(const bf16x8*)(WT + (size_t)(segi * 128 + (i >> 4)) * 128 + (i & 15) * 8);
    }
  };
  auto commitW = [&](){
    #pragma unroll
    for (int r = 0; r < 8; r++) {
      int i = tid + r * 256;
      *(bf16x8*)&Bs[(i >> 4) * BP + (i & 15) * 8] = wreg[r];
    }
  };

  loadW(0); commitW();
  __syncthreads();

  #pragma unroll 1
  for (int seg = 0; seg < 3; seg++) {
    if (seg + 1 < 3) loadW(seg + 1);       // in flight during MFMA
    f32x4 acc[8];
    #pragma unroll
    for (int nt = 0; nt < 8; nt++) acc[nt] = (f32x4){0.f, 0.f, 0.f, 0.f};
    #pragma unroll
    for (int kk = 0; kk < 4; kk++)
      #pragma unroll
      for (int nt = 0; nt < 8; nt++) {
        bf16x8 b = *(const bf16x8*)(&Bs[(nt * 16 + l16) * BP + kk * 32 + quad * 8]);
        acc[nt] = __builtin_amdgcn_mfma_f32_16x16x32_bf16(a[kk], b, acc[nt], 0, 0, 0);
      }
    #pragma unroll
    for (int nt = 0; nt < 8; nt++) {
      int col = seg * 128 + nt * 16 + l16;
      float bv = bf2f(bias[col]);
      #pragma unroll
      for (int r = 0; r < 4; r++) {
        float v = acc[nt][r] + bv;
        if (seg == 0) v *= QSCALE;
        outp[(size_t)(row0 + quad * 4 + r) * 384 + col] = f2bf(v);
      }
    }
    if (seg + 1 < 3) {
      __syncthreads();          // all Bs reads done
      commitW();                // pure LDS writes, no global latency
      __syncthreads();          // Bs ready
    }
  }
}

// ---------------- merged spa+spe chains: ONE canx read, 5 GEMM stages -----
// Weights for stage s+1 register-prefetched during stage s's MFMA, so each
// inter-barrier phase has no exposed global latency. Bit-identical values.
__global__ __launch_bounds__(256) void gemm_chain2(
    const ushort* __restrict__ A,
    const ushort* __restrict__ Wspa1, const ushort* __restrict__ Bspa1,
    const ushort* __restrict__ Wspa2, const ushort* __restrict__ Bspa2,
    const ushort* __restrict__ Wspe1, const ushort* __restrict__ Bspe1,
    const ushort* __restrict__ Wspe2, const ushort* __restrict__ Bspe2,
    const ushort* __restrict__ Wproj,
    ushort* __restrict__ outT, ushort* __restrict__ outH)
{
  constexpr int BP = 136;
  __shared__ ushort Bs[128 * BP];   // 34 KB weight staging
  __shared__ ushort Ts[64 * BP];    // 17 KB intermediate
  int tid = threadIdx.x;
  int lane = tid & 63, wave = tid >> 6;
  int quad = lane >> 4, l16 = lane & 15;
  int row0 = blockIdx.x * 64 + wave * 16;
  int lw = wave * 16;

  // canx fragments: loaded once, reused by stage 1 (spa) and stage 3 (spe)
  bf16x8 ax[4];
  {
    const ushort* ap = A + (size_t)(row0 + l16) * 128 + quad * 8;
    #pragma unroll
    for (int kk = 0; kk < 4; kk++) ax[kk] = *(const bf16x8*)(ap + kk * 32);
  }

  f32x4 acc[8];
  bf16x8 at[4];
  bf16x8 wreg[8];

  auto loadW = [&](const ushort* Wp){
    #pragma unroll
    for (int r = 0; r < 8; r++) {
      int i = tid + r * 256;
      wreg[r] = *(const bf16x8*)(Wp + (size_t)(i >> 4) * 128 + (i & 15) * 8);
    }
  };
  auto commitW = [&](){
    #pragma unroll
    for (int r = 0; r < 8; r++) {
      int i = tid + r * 256;
      *(bf16x8*)&Bs[(i >> 4) * BP + (i & 15) * 8] = wreg[r];
    }
  };
  auto mfmaA = [&](const bf16x8* av){
    #pragma unroll
    for (int nt = 0; nt < 8; nt++) acc[nt] = (f32x4){0.f, 0.f, 0.f, 0.f};
    #pragma unroll
    for (int kk = 0; kk < 4; kk++)
      #pragma unroll
      for (int nt = 0; nt < 8; nt++) {
        bf16x8 b = *(const bf16x8*)(&Bs[(nt * 16 + l16) * BP + kk * 32 + quad * 8]);
        acc[nt] = __builtin_amdgcn_mfma_f32_16x16x32_bf16(av[kk], b, acc[nt], 0, 0, 0);
      }
  };
  auto loadTs = [&](){
    #pragma unroll
    for (int kk = 0; kk < 4; kk++)
      at[kk] = *(const bf16x8*)(&Ts[(lw + l16) * BP + kk * 32 + quad * 8]);
  };
  auto writeTs = [&](const ushort* Bp, bool relu){
    #pragma unroll
    for (int nt = 0; nt < 8; nt++) {
      int col = nt * 16 + l16;
      float bv = bf2f(Bp[col]);
      #pragma unroll
      for (int r = 0; r < 4; r++) {
        float v = acc[nt][r] + bv;
        if (relu) v = fmaxf(v, 0.f);
        Ts[(lw + quad * 4 + r) * BP + col] = f2bf(v);
      }
    }
  };

  loadW(Wspa1); commitW();
  __syncthreads();
  // ---- stage 1: relu(x@spa1 + b) -> Ts ----
  loadW(Wspa2);                          // prefetch next
  mfmaA(ax); writeTs(Bspa1, true);
  __syncthreads();
  commitW(); loadTs();
  __syncthreads();
  // ---- stage 2: Ts@spa2 + b -> Tbig (stride 640) ----
  loadW(Wspe1);
  mfmaA(at);
  #pragma unroll
  for (int nt = 0; nt < 8; nt++) {
    int col = nt * 16 + l16;
    float bv = bf2f(Bspa2[col]);
    #pragma unroll
    for (int r = 0; r < 4; r++)
      outT[(size_t)(row0 + quad * 4 + r) * 640 + col] = f2bf(acc[nt][r] + bv);
  }
  __syncthreads();
  commitW();
  __syncthreads();
  // ---- stage 3: relu(x@spe1 + b) -> Ts (reuses ax) ----
  loadW(Wspe2);
  mfmaA(ax); writeTs(Bspe1, true);
  __syncthreads();
  commitW(); loadTs();
  __syncthreads();
  // ---- stage 4: Ts@spe2 + b -> Ts ----
  loadW(Wproj);
  mfmaA(at); writeTs(Bspe2, false);
  __syncthreads();
  commitW(); loadTs();
  __syncthreads();
  // ---- stage 5: Ts@proj -> hproj ----
  mfmaA(at);
  #pragma unroll
  for (int nt = 0; nt < 8; nt++) {
    int col = nt * 16 + l16;
    #pragma unroll
    for (int r = 0; r < 4; r++)
      outH[(size_t)(row0 + quad * 4 + r) * 128 + col] = f2bf(acc[nt][r]);
  }
}

// ---------------- fused MLP with in-kernel BN1+BN2 combine ----------------
// 4 weight-staging phases, each register-prefetched during the prior MFMA.
__global__ __launch_bounds__(256) void gemm_mlp(
    const float* __restrict__ F1a, const float* __restrict__ F1b,
    const float* __restrict__ st1, const float* __restrict__ st2,
    const ushort* __restrict__ bw1, const ushort* __restrict__ bb1,
    const ushort* __restrict__ bw2, const ushort* __restrict__ bb2,
    const ushort* __restrict__ W1, const ushort* __restrict__ B1,
    const ushort* __restrict__ W2, const ushort* __restrict__ B2,
    float* __restrict__ outp, float* __restrict__ gstats)
{
  constexpr int BP = 136;
  constexpr int HP = 264;
  __shared__ ushort Bs[128 * BP];   // 34 KB weight staging
  __shared__ ushort Hs[64 * HP];    // 33 KB hidden (64 x 256, pad 8)
  __shared__ float ls[256];
  __shared__ float kc1[128], oc1[128], kc2[128], oc2[128];
  int tid = threadIdx.x;
  int lane = tid & 63, wave = tid >> 6;
  int quad = lane >> 4, l16 = lane & 15;
  int row0 = blockIdx.x * 64 + wave * 16;
  int lw = wave * 16;

  bf16x8 wreg[8];
  auto loadW = [&](const ushort* Wp, int stride, int koff){
    #pragma unroll
    for (int r = 0; r < 8; r++) {
      int i = tid + r * 256;
      wreg[r] = *(const bf16x8*)(Wp + (size_t)(i >> 4) * stride + koff + (i & 15) * 8);
    }
  };
  auto commitW = [&](){
    #pragma unroll
    for (int r = 0; r < 8; r++) {
      int i = tid + r * 256;
      *(bf16x8*)&Bs[(i >> 4) * BP + (i & 15) * 8] = wreg[r];
    }
  };

  // fold 8-replica BN stats -> affine coefs
  if (tid < 128) {
    float s = 0.f, s2 = 0.f, t = 0.f, t2 = 0.f;
    #pragma unroll
    for (int rr = 0; rr < 8; rr++) {
      s  += st1[rr * 256 + tid];  s2 += st1[rr * 256 + 128 + tid];
      t  += st2[rr * 256 + tid];  t2 += st2[rr * 256 + 128 + tid];
    }
    float mu  = s * (1.f / 32768.f);
    float var = fmaxf(s2 * (1.f / 32768.f) - mu * mu, 0.f);
    float k = rsqrtf(var + EPSV) * bf2f(bw1[tid]);
    kc1[tid] = k; oc1[tid] = bf2f(bb1[tid]) - mu * k;
    mu  = t * (1.f / 32768.f);
    var = fmaxf(t2 * (1.f / 32768.f) - mu * mu, 0.f);
    k = rsqrtf(var + EPSV) * bf2f(bw2[tid]);
    kc2[tid] = k; oc2[tid] = bf2f(bb2[tid]) - mu * k;
  }
  loadW(W1, 128, 0);               // seg0 weights in flight during coef sync
  __syncthreads();

  // A fragments = comb(row0+l16, :) computed from F1a/F1b
  bf16x8 a[4];
  {
    int arow = row0 + l16;
    const float* pa = F1a + (size_t)arow * 128;
    const float* pb = F1b + (size_t)arow * 128;
    #pragma unroll
    for (int kk = 0; kk < 4; kk++) {
      int c0 = kk * 32 + quad * 8;
      float4 xa0 = *(const float4*)(pa + c0);
      float4 xa1 = *(const float4*)(pa + c0 + 4);
      float4 xb0 = *(const float4*)(pb + c0);
      float4 xb1 = *(const float4*)(pb + c0 + 4);
      float xa[8] = {xa0.x, xa0.y, xa0.z, xa0.w, xa1.x, xa1.y, xa1.z, xa1.w};
      float xb[8] = {xb0.x, xb0.y, xb0.z, xb0.w, xb1.x, xb1.y, xb1.z, xb1.w};
      bf16x8 frag;
      #pragma unroll
      for (int j = 0; j < 8; j++) {
        int c = c0 + j;
        float h1v = bf2f(f2bf(sane(xa[j]) * kc1[c] + oc1[c]));
        frag[j] = (short)f2bf(sane(xb[j]) * kc2[c] + oc2[c] + h1v);
      }
      a[kk] = frag;
    }
  }
  commitW();
  __syncthreads();

  for (int seg = 0; seg < 2; seg++) {
    if (seg == 0) loadW(W1, 128, 128 * 128);   // prefetch seg1
    else          loadW(W2, 256, 0);           // prefetch W2 kc0
    f32x4 acc[8];
    #pragma unroll
    for (int nt = 0; nt < 8; nt++) acc[nt] = (f32x4){0.f, 0.f, 0.f, 0.f};
    #pragma unroll
    for (int kk = 0; kk < 4; kk++)
      #pragma unroll
      for (int nt = 0; nt < 8; nt++) {
        bf16x8 b = *(const bf16x8*)(&Bs[(nt * 16 + l16) * BP + kk * 32 + quad * 8]);
        acc[nt] = __builtin_amdgcn_mfma_f32_16x16x32_bf16(a[kk], b, acc[nt], 0, 0, 0);
      }
    #pragma unroll
    for (int nt = 0; nt < 8; nt++) {
      int col = seg * 128 + nt * 16 + l16;
      float bv = bf2f(B1[col]);
      #pragma unroll
      for (int r = 0; r < 4; r++)
        Hs[(lw + quad * 4 + r) * HP + col] = f2bf(fmaxf(acc[nt][r] + bv, 0.f));
    }
    __syncthreads();
    commitW();
    __syncthreads();
  }
  if (tid < 256) ls[tid] = 0.f;

  f32x4 acc2[8];
  #pragma unroll
  for (int nt = 0; nt < 8; nt++) acc2[nt] = (f32x4){0.f, 0.f, 0.f, 0.f};
  for (int kc = 0; kc < 2; kc++) {
    if (kc == 0) loadW(W2, 256, 128);          // prefetch kc1
    bf16x8 a2[4];
    #pragma unroll
    for (int kk = 0; kk < 4; kk++)
      a2[kk] = *(const bf16x8*)(&Hs[(lw + l16) * HP + kc * 128 + kk * 32 + quad * 8]);
    #pragma unroll
    for (int kk = 0; kk < 4; kk++)
      #pragma unroll
      for (int nt = 0; nt < 8; nt++) {
        bf16x8 b = *(const bf16x8*)(&Bs[(nt * 16 + l16) * BP + kk * 32 + quad * 8]);
        acc2[nt] = __builtin_amdgcn_mfma_f32_16x16x32_bf16(a2[kk], b, acc2[nt], 0, 0, 0);
      }
    if (kc == 0) {
      __syncthreads();
      commitW();
      __syncthreads();
    }
  }

  #pragma unroll
  for (int nt = 0; nt < 8; nt++) {
    int col = nt * 16 + l16;
    float bv = bf2f(B2[col]);
    float cs_ = 0.f, cs2 = 0.f;
    #pragma unroll
    for (int r = 0; r < 4; r++) {
      int row = row0 + quad * 4 + r;
      // recompute comb residual (identical rounding to A fragments)
      float xa = sane(F1a[(size_t)row * 128 + col]);
      float xb = sane(F1b[(size_t)row * 128 + col]);
      float h1v = bf2f(f2bf(xa * kc1[col] + oc1[col]));
      ushort cb = f2bf(xb * kc2[col] + oc2[col] + h1v);
      float v = acc2[nt][r] + bv + bf2f(cb);
      outp[(size_t)row * 128 + col] = v;
      float sv = sane(v); cs_ += sv; cs2 += sv * sv;
    }
    atomicAdd(&ls[col], cs_); atomicAdd(&ls[128 + col], cs2);
  }
  __syncthreads();
  float* gs = gstats + (blockIdx.x & 7) * 256;
  if (tid < 128) {
    atomicAdd(&gs[tid], ls[tid]);
    atomicAdd(&gs[128 + tid], ls[128 + tid]);
  }
}

// ---------------- fused lhat / Chebyshev recurrence (4-wide gather) --------
__global__ __launch_bounds__(256) void spmm_cheb(
    const int* __restrict__ row_ptr, const int2* __restrict__ ep,
    const ushort* __restrict__ v,
    const ushort* __restrict__ txprev, ushort* __restrict__ txout,
    const ushort* __restrict__ lambda_max, int first, int str)
{
  int wave = threadIdx.x >> 6, lane = threadIdx.x & 63;
  int sub = lane >> 4, l16 = lane & 15;
  int d = blockIdx.x * 4 + wave;
  float lm = bf2f(lambda_max[0]);
  float scale = 2.f / lm;
  if (!(scale == scale) || fabsf(scale) > 1e6f) scale = 1.f;
  int beg = row_ptr[d];
  int end = (d == N - 1) ? E : row_ptr[d + 1];
  float acc[8] = {0.f,0.f,0.f,0.f,0.f,0.f,0.f,0.f};
  for (int jb = beg; jb < end; jb += 16) {
    int j0 = jb + sub, j1 = jb + 4 + sub, j2 = jb + 8 + sub, j3 = jb + 12 + sub;
    int2 e0 = ep[j0 < end ? j0 : 0];
    int2 e1 = ep[j1 < end ? j1 : 0];
    int2 e2 = ep[j2 < end ? j2 : 0];
    int2 e3 = ep[j3 < end ? j3 : 0];
    bf16x8 v0 = *(const bf16x8*)(v + (size_t)(e0.x & (N - 1)) * str + l16 * 8);
    bf16x8 v1 = *(const bf16x8*)(v + (size_t)(e1.x & (N - 1)) * str + l16 * 8);
    bf16x8 v2 = *(const bf16x8*)(v + (size_t)(e2.x & (N - 1)) * str + l16 * 8);
    bf16x8 v3 = *(const bf16x8*)(v + (size_t)(e3.x & (N - 1)) * str + l16 * 8);
    float w0 = j0 < end ? __int_as_float(e0.y) : 0.f;
    float w1 = j1 < end ? __int_as_float(e1.y) : 0.f;
    float w2 = j2 < end ? __int_as_float(e2.y) : 0.f;
    float w3 = j3 < end ? __int_as_float(e3.y) : 0.f;
    #pragma unroll
    for (int i = 0; i < 8; i++) acc[i] += w0 * bf2f((ushort)v0[i]);
    #pragma unroll
    for (int i = 0; i < 8; i++) acc[i] += w1 * bf2f((ushort)v1[i]);
    #pragma unroll
    for (int i = 0; i < 8; i++) acc[i] += w2 * bf2f((ushort)v2[i]);
    #pragma unroll
    for (int i = 0; i < 8; i++) acc[i] += w3 * bf2f((ushort)v3[i]);
  }
  #pragma unroll
  for (int i = 0; i < 8; i++) {
    acc[i] += __shfl_xor(acc[i], 16);
    acc[i] += __shfl_xor(acc[i], 32);
  }
  if (sub == 0) {
    bf16x8 vd = *(const bf16x8*)(v + (size_t)d * str + l16 * 8);
    bf16x8 tp;
    if (!first) tp = *(const bf16x8*)(txprev + (size_t)d * str + l16 * 8);
    bf16x8 ov;
    #pragma unroll
    for (int i = 0; i < 8; i++) {
      float r = (scale - 1.f) * bf2f((ushort)vd[i]) - scale * acc[i];
      if (!first) r = 2.f * r - bf2f((ushort)tp[i]);
      ov[i] = (short)f2bf(r);
    }
    *(bf16x8*)(txout + (size_t)d * str + l16 * 8) = ov;
  }
}

// ---------------- U^T @ h_proj partials via MFMA (256 blocks, full GPU) ----
__global__ __launch_bounds__(256) void ut_mfma(const ushort* __restrict__ U,
    const ushort* __restrict__ hp, float* __restrict__ parts)
{
  constexpr int RP = 40;
  __shared__ ushort Ut[128 * RP];
  __shared__ ushort Ht[128 * RP];
  int t = threadIdx.x;
  int lane = t & 63, wave = t >> 6;
  int quad = lane >> 4, l16 = lane & 15;

  f32x4 acc[2][8];
  #pragma unroll
  for (int a = 0; a < 2; a++)
    #pragma unroll
    for (int ct = 0; ct < 8; ct++) acc[a][ct] = (f32x4){0.f, 0.f, 0.f, 0.f};

  for (int ch = 0; ch < 4; ch++) {
    int n0 = blockIdx.x * 128 + ch * 32;
    __syncthreads();
    for (int i = t; i < 2048; i += 256) {
      int r2 = i >> 7, c = i & 127;
      uint u0 = U [(size_t)(n0 + r2 * 2) * 128 + c];
      uint u1 = U [(size_t)(n0 + r2 * 2 + 1) * 128 + c];
      *(uint*)&Ut[c * RP + r2 * 2] = (u0 & 0xffffu) | (u1 << 16);
      uint h0 = hp[(size_t)(n0 + r2 * 2) * 128 + c];
      uint h1 = hp[(size_t)(n0 + r2 * 2 + 1) * 128 + c];
      *(uint*)&Ht[c * RP + r2 * 2] = (h0 & 0xffffu) | (h1 << 16);
    }
    __syncthreads();
    bf16x8 bfr[8];
    #pragma unroll
    for (int ct = 0; ct < 8; ct++)
      bfr[ct] = *(const bf16x8*)(&Ht[(ct * 16 + l16) * RP + quad * 8]);
    #pragma unroll
    for (int a = 0; a < 2; a++) {
      int kt = wave * 2 + a;
      bf16x8 af = *(const bf16x8*)(&Ut[(kt * 16 + l16) * RP + quad * 8]);
      #pragma unroll
      for (int ct = 0; ct < 8; ct++)
        acc[a][ct] = __builtin_amdgcn_mfma_f32_16x16x32_bf16(af, bfr[ct], acc[a][ct], 0, 0, 0);
    }
  }

  float* po = parts + (size_t)blockIdx.x * 16384;
  #pragma unroll
  for (int a = 0; a < 2; a++) {
    int kt = wave * 2 + a;
    #pragma unroll
    for (int ct = 0; ct < 8; ct++)
      #pragma unroll
      for (int r = 0; r < 4; r++)
        po[(kt * 16 + quad * 4 + r) * 128 + ct * 16 + l16] = acc[a][ct][r];
  }
}

__global__ __launch_bounds__(256) void reduce_mt(const float* __restrict__ parts,
    const ushort* __restrict__ Lambda, const ushort* __restrict__ gamma,
    ushort* __restrict__ MT)
{
  int e = blockIdx.x * 256 + threadIdx.x;
  int keig = e >> 7, c = e & 127;
  float s = 0.f;
  for (int p = 0; p < UT_BLOCKS; p++) s += parts[(size_t)p * 16384 + e];
  float g = bf2f(gamma[0]);
  float lam = bf2f(Lambda[keig]);
  float sl = __expf(-g * lam * lam);
  MT[c * 128 + keig] = f2bf(sl * s);
}

// ---------------- BatchNorm apply (stats from 8 replicated bins) ----------
__global__ __launch_bounds__(256) void bn_apply(const float* __restrict__ h,
    const float* __restrict__ st, const ushort* __restrict__ gw,
    const ushort* __restrict__ gb, const ushort* __restrict__ add,
    void* __restrict__ out, const uint* __restrict__ lmraw, int final_out)
{
  __shared__ float sk[128], sb[128];
  int tid = threadIdx.x;
  if (tid < 128) {
    float s = 0.f, s2 = 0.f;
    #pragma unroll
    for (int rr = 0; rr < 8; rr++) {
      s  += st[rr * 256 + tid];
      s2 += st[rr * 256 + 128 + tid];
    }
    float mu  = s * (1.f / 32768.f);
    float var = fmaxf(s2 * (1.f / 32768.f) - mu * mu, 0.f);
    float k = rsqrtf(var + EPSV) * bf2f(gw[tid]);
    sk[tid] = k;
    sb[tid] = bf2f(gb[tid]) - mu * k;
  }
  __syncthreads();
  size_t e = ((size_t)blockIdx.x * 256 + tid) * 4;
  int c0 = (int)(e & 127);
  float4 hv = *(const float4*)(h + e);
  float xv[4] = {sane(hv.x), sane(hv.y), sane(hv.z), sane(hv.w)};
  float addv[4] = {0.f, 0.f, 0.f, 0.f};
  if (add) {
    ushort4 av = *(const ushort4*)(add + e);
    addv[0] = bf2f(av.x); addv[1] = bf2f(av.y);
    addv[2] = bf2f(av.z); addv[3] = bf2f(av.w);
  }
  float r[4];
  #pragma unroll
  for (int j = 0; j < 4; j++) {
    int c = c0 + j;
    r[j] = xv[j] * sk[c] + sb[c] + addv[j];
  }
  if (final_out && mode_fp32(lmraw)) {
    float4 o4; o4.x = r[0]; o4.y = r[1]; o4.z = r[2]; o4.w = r[3];
    *(float4*)((float*)out + e) = o4;
  } else {
    ushort4 o;
    o.x = f2bf(r[0]); o.y = f2bf(r[1]); o.z = f2bf(r[2]); o.w = f2bf(r[3]);
    *(ushort4*)((ushort*)out + e) = o;
  }
}

// ---------------- MFMA flash attention ----------------
__global__ __launch_bounds__(512) void attn_mfma(const ushort* __restrict__ qkv,
                                                 ushort* __restrict__ attn)
{
  constexpr int VP = 516;            // 258 words = 2 mod 32
  constexpr int KP = 40;             // 20 words -> 2-way max on b128 (free)
  __shared__ ushort Kt[512 * KP];    // 40 KB  [key][dim]
  __shared__ ushort Vt[32 * VP];     // 33 KB  [dim][key]
  int b = blockIdx.x;
  int g = b >> 3, hh = (b >> 1) & 3, half = b & 1;
  int lane = threadIdx.x & 63, wave = threadIdx.x >> 6;   // wave 0..7
  int quad = lane >> 4, l16 = lane & 15;
  const ushort* base = qkv + (size_t)g * 512 * 384;

  for (int i = threadIdx.x; i < 512 * 4; i += 512) {
    int key = i >> 2, c8 = (i & 3) * 8;
    *(bf16x8*)&Kt[key * KP + c8] =
        *(const bf16x8*)(base + (size_t)key * 384 + 128 + hh * 32 + c8);
  }
  for (int i = threadIdx.x; i < 256 * 8; i += 512) {
    int kp = i >> 3, d4 = (i & 7) * 4;
    const ushort* va = base + (size_t)(2 * kp) * 384 + 256 + hh * 32 + d4;
    ushort4 a = *(const ushort4*)va;
    ushort4 c = *(const ushort4*)(va + 384);
    *(uint*)&Vt[(d4 + 0) * VP + 2 * kp] = (uint)a.x | ((uint)c.x << 16);
    *(uint*)&Vt[(d4 + 1) * VP + 2 * kp] = (uint)a.y | ((uint)c.y << 16);
    *(uint*)&Vt[(d4 + 2) * VP + 2 * kp] = (uint)a.z | ((uint)c.z << 16);
    *(uint*)&Vt[(d4 + 3) * VP + 2 * kp] = (uint)a.w | ((uint)c.w << 16);
  }
  __syncthreads();

  int q0 = half * 256 + wave * 32;
  bf16x8 qf[2];
  #pragma unroll
  for (int i = 0; i < 2; i++)
    qf[i] = *(const bf16x8*)(base + (size_t)(q0 + i * 16 + l16) * 384 + hh * 32 + quad * 8);

  f32x4 O[2][2];
  #pragma unroll
  for (int dt = 0; dt < 2; dt++)
    #pragma unroll
    for (int i = 0; i < 2; i++) O[dt][i] = (f32x4){0.f, 0.f, 0.f, 0.f};
  float lsum[2] = {0.f, 0.f};

  union PU { uint u[4]; bf16x8 v; };
  union VU { uint2 a[2]; bf16x8 v; };

  for (int kt2 = 0; kt2 < 16; kt2++) {
    int k0 = kt2 * 32;
    bf16x8 kfA = *(const bf16x8*)&Kt[(k0 + l16) * KP + quad * 8];
    bf16x8 kfB = *(const bf16x8*)&Kt[(k0 + 16 + l16) * KP + quad * 8];
    PU pw[2];
    #pragma unroll
    for (int i = 0; i < 2; i++) {
      f32x4 sA = __builtin_amdgcn_mfma_f32_16x16x32_bf16(kfA, qf[i], (f32x4){0.f,0.f,0.f,0.f}, 0, 0, 0);
      f32x4 sB = __builtin_amdgcn_mfma_f32_16x16x32_bf16(kfB, qf[i], (f32x4){0.f,0.f,0.f,0.f}, 0, 0, 0);
      float p0 = fexp2(fminf(sA[0], 86.5f));
      float p1 = fexp2(fminf(sA[1], 86.5f));
      float p2 = fexp2(fminf(sA[2], 86.5f));
      float p3 = fexp2(fminf(sA[3], 86.5f));
      float p4 = fexp2(fminf(sB[0], 86.5f));
      float p5 = fexp2(fminf(sB[1], 86.5f));
      float p6 = fexp2(fminf(sB[2], 86.5f));
      float p7 = fexp2(fminf(sB[3], 86.5f));
      lsum[i] += ((p0 + p1) + (p2 + p3)) + ((p4 + p5) + (p6 + p7));
      pw[i].u[0] = cvtpk(p0, p1); pw[i].u[1] = cvtpk(p2, p3);
      pw[i].u[2] = cvtpk(p4, p5); pw[i].u[3] = cvtpk(p6, p7);
    }
    #pragma unroll
    for (int dt = 0; dt < 2; dt++) {
      int drow = (dt * 16 + l16) * VP;
      VU vu;
      vu.a[0] = *(const uint2*)&Vt[drow + k0 + quad * 4];
      vu.a[1] = *(const uint2*)&Vt[drow + k0 + 16 + quad * 4];
      #pragma unroll
      for (int i = 0; i < 2; i++)
        O[dt][i] = __builtin_amdgcn_mfma_f32_16x16x32_bf16(vu.v, pw[i].v, O[dt][i], 0, 0, 0);
    }
  }

  #pragma unroll
  for (int i = 0; i < 2; i++) {
    float l = lsum[i];
    l += __shfl_xor(l, 16);
    l += __shfl_xor(l, 32);
    lsum[i] = 1.f / l;
  }

  #pragma unroll
  for (int i = 0; i < 2; i++) {
    size_t node = (size_t)g * 512 + q0 + i * 16 + l16;
    #pragma unroll
    for (int dt = 0; dt < 2; dt++) {
      uint2 o;
      o.x = cvtpk(O[dt][i][0] * lsum[i], O[dt][i][1] * lsum[i]);
      o.y = cvtpk(O[dt][i][2] * lsum[i], O[dt][i][3] * lsum[i]);
      *(uint2*)(attn + node * 128 + hh * 32 + dt * 16 + quad * 4) = o;
    }
  }
}

// ---------------- workspace layout (bytes), total 103 MB ----------------
constexpr size_t KB = 1024;
constexpr size_t MB = 1048576;
constexpr size_t OFF_WT    = 0;                 // 576 KB
constexpr size_t OFF_CDT   = 576 * KB;          // 128 KB (cnt_dst totals)
constexpr size_t OFF_RP    = 704 * KB;          // 128 KB
constexpr size_t OFF_DIS   = 832 * KB;          // 128 KB
constexpr size_t OFF_MT    = 960 * KB;          // 32 KB
constexpr size_t OFF_STATS = 1024 * KB;         // 24 KB (3 BN x 8 reps x 256 f32) [zeroed]
constexpr size_t OFF_CEI   = 6  * MB;           // 4 MB
constexpr size_t OFF_EP    = 10 * MB;           // 4 MB (packed int2 per slot)
constexpr size_t OFF_CANX  = 14 * MB;           // 8 MB
constexpr size_t OFF_CANU  = 22 * MB;           // 8 MB
constexpr size_t OFF_CANS  = 30 * MB;           // ~0.6 MB
constexpr size_t OFF_F1    = 31 * MB;           // fp32 16 MB (F1a)
constexpr size_t OFF_HPROJ = 39 * MB;           // 8 MB (dead before F1a write)
constexpr size_t OFF_TBIG  = 47 * MB;           // 40 MB cheb T; later qkvb+F1B
constexpr size_t OFF_PARTH = OFF_TBIG;          // 16 MB hist partials
constexpr size_t OFF_OFF2  = OFF_TBIG + 16 * MB;// 16 MB per-block slot bases
constexpr size_t OFF_F1B   = 71 * MB;           // fp32 16 MB (Tbig tail)
constexpr size_t OFF_PARTS = 87 * MB;           // 16 MB; attnb shares; end 103 MB

extern "C" void kernel_launch(void* const* d_in, const int* in_sizes, int n_in,
                              void* d_out, int out_size, void* d_ws, size_t ws_size,
                              hipStream_t stream) {
  (void)in_sizes; (void)n_in; (void)out_size; (void)ws_size;
  const uint* lmraw = (const uint*)d_in[3];
  const int*  ei    = (const int*)d_in[30];

  char* W = (char*)d_ws;
  ushort* wt    = (ushort*)(W + OFF_WT);
  int*    cdt   = (int*)(W + OFF_CDT);
  int*    rp    = (int*)(W + OFF_RP);
  float*  dis   = (float*)(W + OFF_DIS);
  ushort* MT    = (ushort*)(W + OFF_MT);
  float*  stats = (float*)(W + OFF_STATS);
  int*    cei   = (int*)(W + OFF_CEI);
  int2*   ep    = (int2*)(W + OFF_EP);
  ushort* part  = (ushort*)(W + OFF_PARTH);
  int*    off2  = (int*)(W + OFF_OFF2);
  ushort* canx  = (ushort*)(W + OFF_CANX);
  ushort* canu  = (ushort*)(W + OFF_CANU);
  ushort* cs    = (ushort*)(W + OFF_CANS);
  float*  F1    = (float*)(W + OFF_F1);
  float*  F1B   = (float*)(W + OFF_F1B);
  ushort* hproj = (ushort*)(W + OFF_HPROJ);
  ushort* Tbig  = (ushort*)(W + OFF_TBIG);
  ushort* qkvb  = (ushort*)(W + OFF_TBIG);
  float*  parts = (float*)(W + OFF_PARTS);
  ushort* attnb = (ushort*)(W + OFF_PARTS);

  const ushort* cLambda = cs + COF[0];
  const ushort* cLmx    = cs + COF[1];
  const ushort* cBspa1  = cs + COF[3];
  const ushort* cBspa2  = cs + COF[5];
  const ushort* cBspe1  = cs + COF[7];
  const ushort* cBspe2  = cs + COF[9];
  const ushort* cChebB  = cs + COF[11];
  const ushort* cGam    = cs + COF[12];
  const ushort* cBqkv   = cs + COF[15];
  const ushort* cBout   = cs + COF[17];
  const ushort* cMb1    = cs + COF[19];
  const ushort* cMb2    = cs + COF[21];
  const ushort* cBn1w   = cs + COF[22];
  const ushort* cBn1b   = cs + COF[23];
  const ushort* cBn2w   = cs + COF[24];
  const ushort* cBn2b   = cs + COF[25];
  const ushort* cBn3w   = cs + COF[26];
  const ushort* cBn3b   = cs + COF[27];

  const ushort* NUL = nullptr;
  float* NULF = nullptr;
  (void)NUL; (void)NULF;

  // ---- fused canonicalize + transpose + zero ----
  CvtArgs ca;
  ca.src[0]  = d_in[2];  ca.src[1]  = d_in[3];  ca.src[2]  = d_in[4];
  ca.src[3]  = d_in[5];  ca.src[4]  = d_in[6];  ca.src[5]  = d_in[7];
  ca.src[6]  = d_in[8];  ca.src[7]  = d_in[9];  ca.src[8]  = d_in[10];
  ca.src[9]  = d_in[11]; ca.src[10] = d_in[12]; ca.src[11] = d_in[13];
  ca.src[12] = d_in[14]; ca.src[13] = d_in[15]; ca.src[14] = d_in[16];
  ca.src[15] = d_in[17]; ca.src[16] = d_in[18]; ca.src[17] = d_in[19];
  ca.src[18] = d_in[20]; ca.src[19] = d_in[21]; ca.src[20] = d_in[22];
  ca.src[21] = d_in[23]; ca.src[22] = d_in[24]; ca.src[23] = d_in[25];
  ca.src[24] = d_in[26]; ca.src[25] = d_in[27]; ca.src[26] = d_in[28];
  ca.src[27] = d_in[29];
  prep_all<<<10530, 256, 0, stream>>>(ca, d_in[0], d_in[1], canx, canu, cs, wt,
                                      (int*)(W + OFF_STATS), lmraw);

  // ---- edge prep (LDS-private histograms, no device-scope atomics) ----
  hist_lds<<<2 * HB, 1024, 0, stream>>>(ei, cei, part);
  reduce_cnt<<<N / 256, 256, 0, stream>>>(part, cdt, dis);
  scan_kernel<<<1, 1024, 0, stream>>>(cdt, rp);
  off_kernel<<<N / 256, 256, 0, stream>>>(rp, part, off2);
  edge_scatter<<<HB, 1024, 0, stream>>>(cei, off2, dis, ep);

  dim3 g1(512), bb(256);
  // ---- merged spa+spe input MLP chains (one canx read, reg-prefetched) ----
  gemm_chain2<<<g1, bb, 0, stream>>>(canx,
      wt + WT_SPA1, cBspa1, wt + WT_SPA2, cBspa2,
      wt + WT_SPE1, cBspe1, wt + WT_SPE2, cBspe2,
      wt + WT_PROJ, Tbig, hproj);

  // ---- spectral filter M^T ----
  ut_mfma<<<UT_BLOCKS, 256, 0, stream>>>(canu, hproj, parts);
  reduce_mt<<<64, 256, 0, stream>>>(parts, cLambda, cGam, MT);

  // ---- Chebyshev recurrence into Tbig ----
  spmm_cheb<<<N / 4, 256, 0, stream>>>(rp, ep, Tbig,       NUL,        Tbig + 128, cLmx, 1, 640);
  spmm_cheb<<<N / 4, 256, 0, stream>>>(rp, ep, Tbig + 128, Tbig,       Tbig + 256, cLmx, 0, 640);
  spmm_cheb<<<N / 4, 256, 0, stream>>>(rp, ep, Tbig + 256, Tbig + 128, Tbig + 384, cLmx, 0, 640);
  spmm_cheb<<<N / 4, 256, 0, stream>>>(rp, ep, Tbig + 384, Tbig + 256, Tbig + 512, cLmx, 0, 640);

  // ---- fused cheb GEMM + spectral MT GEMM + x residual + BN1 stats -> F1a ----
  gemm_cheb_mt<<<g1, bb, 0, stream>>>(Tbig, wt + WT_CHEB, cChebB, canu, MT, canx,
                                      F1, stats);

  // ---- attention branch (Q pre-scaled in QKV epilogue; one A-read) ----
  gemm_qkv<<<g1, bb, 0, stream>>>(canx, wt + WT_QKV, cBqkv, qkvb);
  attn_mfma<<<512, 512, 0, stream>>>(qkvb, attnb);
  gemm_lds<128,128,false,1,true ,true ,128,128,false,true ><<<g1, bb, 0, stream>>>(attnb, wt + WT_WOUT, cBout, canx, F1B, stats + 2048);

  // ---- fused MLP (BN1+BN2 combine in-kernel, +BN3 stats) + final BN ----
  gemm_mlp<<<g1, bb, 0, stream>>>(F1, F1B, stats, stats + 2048,
      cBn1w, cBn1b, cBn2w, cBn2b,
      wt + WT_MLP1, cMb1, wt + WT_MLP2, cMb2, F1, stats + 4096);
  bn_apply<<<(N * C) / 1024, 256, 0, stream>>>(F1, stats + 4096, cBn3w, cBn3b, NUL, d_out, lmraw, 1);
}

// Round 16
// 455.646 us; speedup vs baseline: 1.0268x; 1.0268x over previous
//
#include <hip/hip_runtime.h>

typedef short bf16x8 __attribute__((ext_vector_type(8)));
typedef short bf16x4 __attribute__((ext_vector_type(4)));
typedef float f32x4 __attribute__((ext_vector_type(4)));

#define DEVI __device__ __forceinline__

constexpr int N   = 32768;
constexpr int C   = 128;
constexpr int E   = 524288;
constexpr float EPSV = 1e-5f;
constexpr int UT_BLOCKS = 256;   // each block covers 128 rows (4 chunks of 32)
constexpr int HB  = 128;         // histogram blocks per edge-array (src / dst)
constexpr int EPB = E / HB;      // 4096 edges per histogram block
// softmax scale folded into Q at QKV-GEMM epilogue: 1/sqrt(32) * log2(e)
constexpr float QSCALE = 0.17677669529663687f * 1.4426950408889634f;

DEVI float bf2f(ushort u){ return __uint_as_float(((uint)u) << 16); }
DEVI ushort f2bf(float f){
  uint u = __float_as_uint(f);
  return (ushort)((u + 0x7fffu + ((u >> 16) & 1u)) >> 16);
}
// packed f32 pair -> bf16 pair (round-to-nearest-even), single HW instr
DEVI uint cvtpk(float lo, float hi){
  uint r;
  asm("v_cvt_pk_bf16_f32 %0, %1, %2" : "=v"(r) : "v"(lo), "v"(hi));
  return r;
}
// single-instruction 2^x (no libm edge-case code)
DEVI float fexp2(float x){
  float r;
  asm("v_exp_f32 %0, %1" : "=v"(r) : "v"(x));
  return r;
}
DEVI float sane(float v){ if (!(v == v)) return 0.f; return fminf(fmaxf(v, -1e30f), 1e30f); }
DEVI bool mode_fp32(const uint* lmraw){ return (lmraw[0] & 0xffffu) == 0u; }

// ---------------- canonical small-input table ----------------
constexpr int CSZ[28] = {128,1,16384,128,16384,128,16384,128,16384,128,81920,128,
                         1,16384,49152,384,16384,128,32768,256,32768,128,
                         128,128,128,128,128,128};
constexpr int COF[28] = {0,128,192,16576,16704,33088,33216,49600,49728,66112,
                         66240,148160,148288,148352,164736,213888,214272,230656,
                         230784,263552,263808,296576,296704,296832,296960,297088,
                         297216,297344};
constexpr int CAN_SMALL_TOTAL = 297472;

// ---------------- weight pre-transpose layout ----------------
constexpr int WT_SPA1 = 0;
constexpr int WT_SPA2 = 16384;
constexpr int WT_SPE1 = 32768;
constexpr int WT_SPE2 = 49152;
constexpr int WT_PROJ = 65536;
constexpr int WT_CHEB = 81920;    // 128 x 640 (concat layout)
constexpr int WT_QKV  = 163840;   // 384 x 128
constexpr int WT_WOUT = 212992;
constexpr int WT_MLP1 = 229376;   // 256 x 128
constexpr int WT_MLP2 = 262144;   // 128 x 256
constexpr int WT_TOTAL = 294912;

struct CvtArgs { const void* src[28]; };

DEVI ushort cvt_elem(const void* p, int j, bool f32){
  return f32 ? f2bf(((const float*)p)[j]) : ((const ushort*)p)[j];
}

// ---------------- fused front-end: convert big/small + transpose + zero ----
__global__ __launch_bounds__(256) void prep_all(CvtArgs a,
    const void* __restrict__ xs, const void* __restrict__ Us,
    ushort* __restrict__ canx, ushort* __restrict__ canu,
    ushort* __restrict__ cs, ushort* __restrict__ wt,
    int* __restrict__ zp, const uint* __restrict__ lmraw)
{
  bool f32 = mode_fp32(lmraw);
  int b = blockIdx.x, tid = threadIdx.x;
  if (b < 8192) {
    size_t e = ((size_t)b * 256 + tid) * 4;
    bool isU = e >= (size_t)N * C;
    size_t off = isU ? e - (size_t)N * C : e;
    const void* src = isU ? Us : xs;
    ushort* dst = isU ? canu : canx;
    ushort4 o;
    if (f32) {
      float4 v = *(const float4*)((const float*)src + off);
      o.x = f2bf(v.x); o.y = f2bf(v.y); o.z = f2bf(v.z); o.w = f2bf(v.w);
    } else {
      o = *(const ushort4*)((const ushort*)src + off);
    }
    *(ushort4*)(dst + off) = o;
  } else if (b < 9354) {
    int idx = (b - 8192) * 256 + tid;
    #pragma unroll 1
    for (int s = 0; s < 28; s++) {
      if (idx < CSZ[s]) { cs[COF[s] + idx] = cvt_elem(a.src[s], idx, f32); return; }
      idx -= CSZ[s];
    }
  } else if (b < 10506) {
    int i = (b - 9354) * 256 + tid;
    if (i < 81920) {
      int m = i >> 14, r = i & 16383; int k = r >> 7, n = r & 127;
      const void* src = m==0?a.src[2] : m==1?a.src[4] : m==2?a.src[6] : m==3?a.src[8] : a.src[13];
      wt[m*16384 + n*128 + k] = cvt_elem(src, r, f32);
    } else if (i < 163840) {
      int j = i - 81920; int m = j >> 14, r = j & 16383; int k = r >> 7, n = r & 127;
      wt[WT_CHEB + n*640 + m*128 + k] = cvt_elem(a.src[10], j, f32);
    } else if (i < 212992) {
      int j = i - 163840; int k = j / 384, n = j % 384;
      wt[WT_QKV + n*128 + k] = cvt_elem(a.src[14], j, f32);
    } else if (i < 229376) {
      int j = i - 212992; int k = j >> 7, n = j & 127;
      wt[WT_WOUT + n*128 + k] = cvt_elem(a.src[16], j, f32);
    } else if (i < 262144) {
      int j = i - 229376; int k = j >> 8, n = j & 255;
      wt[WT_MLP1 + n*128 + k] = cvt_elem(a.src[18], j, f32);
    } else if (i < WT_TOTAL) {
      int j = i - 262144; int k = j >> 7, n = j & 127;
      wt[WT_MLP2 + n*256 + k] = cvt_elem(a.src[20], j, f32);
    }
  } else {
    int i = (b - 10506) * 256 + tid;
    if (i < 6144) zp[i] = 0;     // 3 BN x 8 replicas x 256 floats
  }
}

// ---------------- edge prep: LDS-private histograms (no device atomics) ----
__global__ __launch_bounds__(1024) void hist_lds(const int* __restrict__ ei,
    int* __restrict__ cei, ushort* __restrict__ part)
{
  __shared__ uint hist[N / 2];          // 64 KB, two bins per word
  int t = threadIdx.x;
  int b = blockIdx.x;
  bool i64 = ((ei[1] | ei[3] | ei[5] | ei[7]) == 0);
  size_t j0 = (size_t)b * EPB;
  #pragma unroll
  for (int i = t; i < N / 2; i += 1024) hist[i] = 0u;
  __syncthreads();
  for (int k = t; k < EPB; k += 1024) {
    size_t j = j0 + k;
    int v = (i64 ? ei[2 * j] : ei[j]) & (N - 1);
    cei[j] = v;
    atomicAdd(&hist[v >> 1], 1u << ((v & 1) * 16));
  }
  __syncthreads();
  uint* po = (uint*)(part + (size_t)b * N);
  for (int i = t; i < N / 2; i += 1024) po[i] = hist[i];
}

// fold partials: src totals -> dis, dst totals -> cdt
__global__ __launch_bounds__(256) void reduce_cnt(const ushort* __restrict__ part,
    int* __restrict__ cdt, float* __restrict__ dis)
{
  int d = blockIdx.x * 256 + threadIdx.x;
  int s = 0, tt = 0;
  #pragma unroll 8
  for (int b = 0; b < HB; b++) s  += part[(size_t)b * N + d];
  #pragma unroll 8
  for (int b = 0; b < HB; b++) tt += part[(size_t)(HB + b) * N + d];
  cdt[d] = tt;
  dis[d] = s > 0 ? rsqrtf((float)s) : 0.f;
}

__global__ __launch_bounds__(1024) void scan_kernel(const int* __restrict__ cnt,
                                                    int* __restrict__ row_ptr)
{
  __shared__ int sums[1024];
  int t = threadIdx.x;
  int loc[32]; int s = 0;
  int base = t * 32;
  #pragma unroll
  for (int i = 0; i < 32; i++) { loc[i] = s; s += cnt[base + i]; }
  sums[t] = s;
  __syncthreads();
  for (int off = 1; off < 1024; off <<= 1) {
    int v = (t >= off) ? sums[t - off] : 0;
    __syncthreads();
    sums[t] += v;
    __syncthreads();
  }
  int pre = (t == 0) ? 0 : sums[t - 1];
  #pragma unroll
  for (int i = 0; i < 32; i++) row_ptr[base + i] = pre + loc[i];
}

// per-hist-block slot bases: off2[b][d] = rp[d] + sum_{b'<b} partD[b'][d]
__global__ __launch_bounds__(256) void off_kernel(const int* __restrict__ rp,
    const ushort* __restrict__ part, int* __restrict__ off2)
{
  int d = blockIdx.x * 256 + threadIdx.x;
  int run = rp[d];
  #pragma unroll 8
  for (int b = 0; b < HB; b++) {
    off2[(size_t)b * N + d] = run;
    run += part[(size_t)(HB + b) * N + d];
  }
}

// deterministic scatter: block b replays its edge slice, ranks via LDS atomics
__global__ __launch_bounds__(1024) void edge_scatter(const int* __restrict__ cei,
    const int* __restrict__ off2, const float* __restrict__ dis,
    int2* __restrict__ ep)
{
  __shared__ int base[N];               // 128 KB slot cursors
  int t = threadIdx.x;
  int b = blockIdx.x;                   // 0..HB-1
  for (int i = t; i < N; i += 1024) base[i] = off2[(size_t)b * N + i];
  __syncthreads();
  size_t e0 = (size_t)b * EPB;
  for (int k = t; k < EPB; k += 1024) {
    size_t e = e0 + k;
    int s = cei[e], d = cei[e + E];
    int slot = atomicAdd(&base[d], 1);
    int2 v; v.x = s; v.y = __float_as_int(dis[s] * dis[d]);
    ep[slot] = v;
  }
}

// ---------------- LDS-staged MFMA GEMM (optional fused BN-stats) ----------
template<int K, int COLS, bool RELU, int OMODE, bool BIAS, bool RES, int ASTR, int OSTR, bool QSC, bool STATS>
__global__ __launch_bounds__(256) void gemm_lds(
    const ushort* __restrict__ A, const ushort* __restrict__ WT,
    const ushort* __restrict__ bias, const ushort* __restrict__ res,
    void* __restrict__ outp, float* __restrict__ gstats)
{
  constexpr int NSEG = COLS / 128;
  constexpr int NKC = K / 128;
  constexpr int BP = 136;
  __shared__ ushort Bs[128 * BP];
  __shared__ float ls[STATS ? 256 : 1];
  int tid = threadIdx.x;
  int lane = tid & 63, wave = tid >> 6;
  int quad = lane >> 4, l16 = lane & 15;
  int seg = (NSEG > 1) ? (blockIdx.x % NSEG) : 0;
  int rb  = (NSEG > 1) ? (blockIdx.x / NSEG) : blockIdx.x;
  int row0 = rb * 64 + wave * 16;
  const ushort* wseg = WT + (size_t)(seg * 128) * K;

  f32x4 acc[8];
  #pragma unroll
  for (int nt = 0; nt < 8; nt++) acc[nt] = (f32x4){0.f, 0.f, 0.f, 0.f};

  // preload kc=0 A fragments (overlaps HBM latency with staging below)
  bf16x8 a[4];
  {
    const ushort* ap = A + (size_t)(row0 + l16) * ASTR + quad * 8;
    #pragma unroll
    for (int kk = 0; kk < 4; kk++) a[kk] = *(const bf16x8*)(ap + kk * 32);
  }

  for (int kc = 0; kc < NKC; kc++) {
    if (kc) __syncthreads();
    #pragma unroll
    for (int i = tid; i < 2048; i += 256) {
      int col = i >> 4, ko = (i & 15) * 8;
      *(bf16x8*)&Bs[col * BP + ko] =
          *(const bf16x8*)(wseg + (size_t)col * K + kc * 128 + ko);
    }
    __syncthreads();
    if (kc) {
      const ushort* ap = A + (size_t)(row0 + l16) * ASTR + kc * 128 + quad * 8;
      #pragma unroll
      for (int kk = 0; kk < 4; kk++) a[kk] = *(const bf16x8*)(ap + kk * 32);
    }
    #pragma unroll
    for (int kk = 0; kk < 4; kk++) {
      #pragma unroll
      for (int nt = 0; nt < 8; nt++) {
        bf16x8 b = *(const bf16x8*)(&Bs[(nt * 16 + l16) * BP + kk * 32 + quad * 8]);
        acc[nt] = __builtin_amdgcn_mfma_f32_16x16x32_bf16(a[kk], b, acc[nt], 0, 0, 0);
      }
    }
  }

  if (STATS) {
    if (tid < 256) ls[tid] = 0.f;
    __syncthreads();
  }

  #pragma unroll
  for (int nt = 0; nt < 8; nt++) {
    int col = seg * 128 + nt * 16 + l16;
    float bv = 0.f;
    if (BIAS) bv = bf2f(bias[col]);
    float cs_ = 0.f, cs2 = 0.f;
    #pragma unroll
    for (int r = 0; r < 4; r++) {
      int row = row0 + quad * 4 + r;
      size_t oi = (size_t)row * OSTR + col;
      float v = acc[nt][r] + bv;
      if (RES) v += bf2f(res[(size_t)row * COLS + col]);
      if (RELU) v = fmaxf(v, 0.f);
      if (QSC && col < 128) v *= QSCALE;
      float nv;
      if (OMODE == 0)      { ((ushort*)outp)[oi] = f2bf(v); nv = v; }
      else if (OMODE == 1) { ((float*)outp)[oi] = v; nv = v; }
      else                 { float* fo = (float*)outp + oi; nv = *fo + v; *fo = nv; }
      if (STATS) { float sv = sane(nv); cs_ += sv; cs2 += sv * sv; }
    }
    if (STATS) { atomicAdd(&ls[col], cs_); atomicAdd(&ls[128 + col], cs2); }
  }

  if (STATS) {
    __syncthreads();
    float* gs = gstats + (blockIdx.x & 7) * 256;
    if (tid < 128) {
      atomicAdd(&gs[tid], ls[tid]);
      atomicAdd(&gs[128 + tid], ls[128 + tid]);
    }
  }
}

// ---------------- fused cheb+spectral GEMM (prefetch-all + dbuf) ----------
__global__ __launch_bounds__(256) void gemm_cheb_mt(
    const ushort* __restrict__ Tb, const ushort* __restrict__ Wc,
    const ushort* __restrict__ chebB,
    const ushort* __restrict__ canu, const ushort* __restrict__ MT,
    const ushort* __restrict__ canx,
    float* __restrict__ outp, float* __restrict__ gstats)
{
  constexpr int BP = 136;
  __shared__ ushort Bs[2][128 * BP];   // 69.6 KB double buffer
  __shared__ float ls[256];
  int tid = threadIdx.x;
  int lane = tid & 63, wave = tid >> 6;
  int quad = lane >> 4, l16 = lane & 15;
  int row0 = blockIdx.x * 64 + wave * 16;

  // prefetch ALL A fragments: 24 independent 16B loads
  bf16x8 a0[4], a1[4], a2[4], a3[4], a4[4], a5[4];
  {
    const ushort* tb = Tb   + (size_t)(row0 + l16) * 640 + quad * 8;
    const ushort* cu = canu + (size_t)(row0 + l16) * 128 + quad * 8;
    #pragma unroll
    for (int kk = 0; kk < 4; kk++) {
      a0[kk] = *(const bf16x8*)(tb + 0 * 128 + kk * 32);
      a1[kk] = *(const bf16x8*)(tb + 1 * 128 + kk * 32);
      a2[kk] = *(const bf16x8*)(tb + 2 * 128 + kk * 32);
      a3[kk] = *(const bf16x8*)(tb + 3 * 128 + kk * 32);
      a4[kk] = *(const bf16x8*)(tb + 4 * 128 + kk * 32);
      a5[kk] = *(const bf16x8*)(cu + kk * 32);
    }
  }

  f32x4 acc[8];
  #pragma unroll
  for (int nt = 0; nt < 8; nt++) acc[nt] = (f32x4){0.f, 0.f, 0.f, 0.f};

  // stage chunk 0 into buffer 0
  for (int i = tid; i < 2048; i += 256) {
    int col = i >> 4, ko = (i & 15) * 8;
    *(bf16x8*)&Bs[0][col * BP + ko] = *(const bf16x8*)(Wc + (size_t)col * 640 + ko);
  }
  __syncthreads();

  #pragma unroll
  for (int kc = 0; kc < 6; kc++) {
    int cur = kc & 1;
    if (kc + 1 < 6) {
      for (int i = tid; i < 2048; i += 256) {
        int col = i >> 4, ko = (i & 15) * 8;
        *(bf16x8*)&Bs[cur ^ 1][col * BP + ko] = (kc + 1 == 5)
            ? *(const bf16x8*)(MT + (size_t)col * 128 + ko)
            : *(const bf16x8*)(Wc + (size_t)col * 640 + (kc + 1) * 128 + ko);
      }
    }
    const bf16x8* av = kc == 0 ? a0 : kc == 1 ? a1 : kc == 2 ? a2
                     : kc == 3 ? a3 : kc == 4 ? a4 : a5;
    #pragma unroll
    for (int kk = 0; kk < 4; kk++)
      #pragma unroll
      for (int nt = 0; nt < 8; nt++) {
        bf16x8 b = *(const bf16x8*)(&Bs[cur][(nt * 16 + l16) * BP + kk * 32 + quad * 8]);
        acc[nt] = __builtin_amdgcn_mfma_f32_16x16x32_bf16(av[kk], b, acc[nt], 0, 0, 0);
      }
    __syncthreads();
  }

  if (tid < 256) ls[tid] = 0.f;
  __syncthreads();

  #pragma unroll
  for (int nt = 0; nt < 8; nt++) {
    int col = nt * 16 + l16;
    float bv = bf2f(chebB[col]);
    float cs_ = 0.f, cs2 = 0.f;
    #pragma unroll
    for (int r = 0; r < 4; r++) {
      int row = row0 + quad * 4 + r;
      float v = acc[nt][r] + bv + bf2f(canx[(size_t)row * 128 + col]);
      outp[(size_t)row * 128 + col] = v;
      float sv = sane(v); cs_ += sv; cs2 += sv * sv;
    }
    atomicAdd(&ls[col], cs_); atomicAdd(&ls[128 + col], cs2);
  }
  __syncthreads();
  float* gs = gstats + (blockIdx.x & 7) * 256;
  if (tid < 128) {
    atomicAdd(&gs[tid], ls[tid]);
    atomicAdd(&gs[128 + tid], ls[128 + tid]);
  }
}

// ---------------- QKV GEMM: one A-read, 3 segments, reg-prefetched --------
__global__ __launch_bounds__(256) void gemm_qkv(
    const ushort* __restrict__ A, const ushort* __restrict__ WT,
    const ushort* __restrict__ bias, ushort* __restrict__ outp)
{
  constexpr int BP = 136;
  __shared__ ushort Bs[128 * BP];
  int tid = threadIdx.x;
  int lane = tid & 63, wave = tid >> 6;
  int quad = lane >> 4, l16 = lane & 15;
  int row0 = blockIdx.x * 64 + wave * 16;
  bf16x8 a[4];
  {
    const ushort* ap = A + (size_t)(row0 + l16) * 128 + quad * 8;
    #pragma unroll
    for (int kk = 0; kk < 4; kk++) a[kk] = *(const bf16x8*)(ap + kk * 32);
  }

  bf16x8 wreg[8];
  auto loadW = [&](int segi){
    #pragma unroll
    for (int r = 0; r < 8; r++) {
      int i = tid + r * 256;
      wreg[r] = *(const bf16x8*)(WT + (size_t)(segi * 128 + (i >> 4)) * 128 + (i & 15) * 8);
    }
  };
  auto commitW = [&](){
    #pragma unroll
    for (int r = 0; r < 8; r++) {
      int i = tid + r * 256;
      *(bf16x8*)&Bs[(i >> 4) * BP + (i & 15) * 8] = wreg[r];
    }
  };

  loadW(0); commitW();
  __syncthreads();

  #pragma unroll 1
  for (int seg = 0; seg < 3; seg++) {
    if (seg + 1 < 3) loadW(seg + 1);       // in flight during MFMA
    f32x4 acc[8];
    #pragma unroll
    for (int nt = 0; nt < 8; nt++) acc[nt] = (f32x4){0.f, 0.f, 0.f, 0.f};
    #pragma unroll
    for (int kk = 0; kk < 4; kk++)
      #pragma unroll
      for (int nt = 0; nt < 8; nt++) {
        bf16x8 b = *(const bf16x8*)(&Bs[(nt * 16 + l16) * BP + kk * 32 + quad * 8]);
        acc[nt] = __builtin_amdgcn_mfma_f32_16x16x32_bf16(a[kk], b, acc[nt], 0, 0, 0);
      }
    #pragma unroll
    for (int nt = 0; nt < 8; nt++) {
      int col = seg * 128 + nt * 16 + l16;
      float bv = bf2f(bias[col]);
      #pragma unroll
      for (int r = 0; r < 4; r++) {
        float v = acc[nt][r] + bv;
        if (seg == 0) v *= QSCALE;
        outp[(size_t)(row0 + quad * 4 + r) * 384 + col] = f2bf(v);
      }
    }
    if (seg + 1 < 3) {
      __syncthreads();          // all Bs reads done
      commitW();                // pure LDS writes, no global latency
      __syncthreads();          // Bs ready
    }
  }
}

// ---------------- merged spa+spe chains: ONE canx read, 5 GEMM stages -----
// Weights for stage s+1 register-prefetched during stage s's MFMA, so each
// inter-barrier phase has no exposed global latency. Bit-identical values.
__global__ __launch_bounds__(256) void gemm_chain2(
    const ushort* __restrict__ A,
    const ushort* __restrict__ Wspa1, const ushort* __restrict__ Bspa1,
    const ushort* __restrict__ Wspa2, const ushort* __restrict__ Bspa2,
    const ushort* __restrict__ Wspe1, const ushort* __restrict__ Bspe1,
    const ushort* __restrict__ Wspe2, const ushort* __restrict__ Bspe2,
    const ushort* __restrict__ Wproj,
    ushort* __restrict__ outT, ushort* __restrict__ outH)
{
  constexpr int BP = 136;
  __shared__ ushort Bs[128 * BP];   // 34 KB weight staging
  __shared__ ushort Ts[64 * BP];    // 17 KB intermediate
  int tid = threadIdx.x;
  int lane = tid & 63, wave = tid >> 6;
  int quad = lane >> 4, l16 = lane & 15;
  int row0 = blockIdx.x * 64 + wave * 16;
  int lw = wave * 16;

  // canx fragments: loaded once, reused by stage 1 (spa) and stage 3 (spe)
  bf16x8 ax[4];
  {
    const ushort* ap = A + (size_t)(row0 + l16) * 128 + quad * 8;
    #pragma unroll
    for (int kk = 0; kk < 4; kk++) ax[kk] = *(const bf16x8*)(ap + kk * 32);
  }

  f32x4 acc[8];
  bf16x8 at[4];
  bf16x8 wreg[8];

  auto loadW = [&](const ushort* Wp){
    #pragma unroll
    for (int r = 0; r < 8; r++) {
      int i = tid + r * 256;
      wreg[r] = *(const bf16x8*)(Wp + (size_t)(i >> 4) * 128 + (i & 15) * 8);
    }
  };
  auto commitW = [&](){
    #pragma unroll
    for (int r = 0; r < 8; r++) {
      int i = tid + r * 256;
      *(bf16x8*)&Bs[(i >> 4) * BP + (i & 15) * 8] = wreg[r];
    }
  };
  auto mfmaA = [&](const bf16x8* av){
    #pragma unroll
    for (int nt = 0; nt < 8; nt++) acc[nt] = (f32x4){0.f, 0.f, 0.f, 0.f};
    #pragma unroll
    for (int kk = 0; kk < 4; kk++)
      #pragma unroll
      for (int nt = 0; nt < 8; nt++) {
        bf16x8 b = *(const bf16x8*)(&Bs[(nt * 16 + l16) * BP + kk * 32 + quad * 8]);
        acc[nt] = __builtin_amdgcn_mfma_f32_16x16x32_bf16(av[kk], b, acc[nt], 0, 0, 0);
      }
  };
  auto loadTs = [&](){
    #pragma unroll
    for (int kk = 0; kk < 4; kk++)
      at[kk] = *(const bf16x8*)(&Ts[(lw + l16) * BP + kk * 32 + quad * 8]);
  };
  auto writeTs = [&](const ushort* Bp, bool relu){
    #pragma unroll
    for (int nt = 0; nt < 8; nt++) {
      int col = nt * 16 + l16;
      float bv = bf2f(Bp[col]);
      #pragma unroll
      for (int r = 0; r < 4; r++) {
        float v = acc[nt][r] + bv;
        if (relu) v = fmaxf(v, 0.f);
        Ts[(lw + quad * 4 + r) * BP + col] = f2bf(v);
      }
    }
  };

  loadW(Wspa1); commitW();
  __syncthreads();
  // ---- stage 1: relu(x@spa1 + b) -> Ts ----
  loadW(Wspa2);                          // prefetch next
  mfmaA(ax); writeTs(Bspa1, true);
  __syncthreads();
  commitW(); loadTs();
  __syncthreads();
  // ---- stage 2: Ts@spa2 + b -> Tbig (stride 640) ----
  loadW(Wspe1);
  mfmaA(at);
  #pragma unroll
  for (int nt = 0; nt < 8; nt++) {
    int col = nt * 16 + l16;
    float bv = bf2f(Bspa2[col]);
    #pragma unroll
    for (int r = 0; r < 4; r++)
      outT[(size_t)(row0 + quad * 4 + r) * 640 + col] = f2bf(acc[nt][r] + bv);
  }
  __syncthreads();
  commitW();
  __syncthreads();
  // ---- stage 3: relu(x@spe1 + b) -> Ts (reuses ax) ----
  loadW(Wspe2);
  mfmaA(ax); writeTs(Bspe1, true);
  __syncthreads();
  commitW(); loadTs();
  __syncthreads();
  // ---- stage 4: Ts@spe2 + b -> Ts ----
  loadW(Wproj);
  mfmaA(at); writeTs(Bspe2, false);
  __syncthreads();
  commitW(); loadTs();
  __syncthreads();
  // ---- stage 5: Ts@proj -> hproj ----
  mfmaA(at);
  #pragma unroll
  for (int nt = 0; nt < 8; nt++) {
    int col = nt * 16 + l16;
    #pragma unroll
    for (int r = 0; r < 4; r++)
      outH[(size_t)(row0 + quad * 4 + r) * 128 + col] = f2bf(acc[nt][r]);
  }
}

// ---------------- fused MLP with in-kernel BN1+BN2 combine ----------------
// (round-14 form: direct global->LDS staging, 112 VGPR, 2 blocks/CU)
__global__ __launch_bounds__(256) void gemm_mlp(
    const float* __restrict__ F1a, const float* __restrict__ F1b,
    const float* __restrict__ st1, const float* __restrict__ st2,
    const ushort* __restrict__ bw1, const ushort* __restrict__ bb1,
    const ushort* __restrict__ bw2, const ushort* __restrict__ bb2,
    const ushort* __restrict__ W1, const ushort* __restrict__ B1,
    const ushort* __restrict__ W2, const ushort* __restrict__ B2,
    float* __restrict__ outp, float* __restrict__ gstats)
{
  constexpr int BP = 136;
  constexpr int HP = 264;
  __shared__ ushort Bs[128 * BP];   // 34 KB weight staging
  __shared__ ushort Hs[64 * HP];    // 33 KB hidden (64 x 256, pad 8)
  __shared__ float ls[256];
  __shared__ float kc1[128], oc1[128], kc2[128], oc2[128];
  int tid = threadIdx.x;
  int lane = tid & 63, wave = tid >> 6;
  int quad = lane >> 4, l16 = lane & 15;
  int row0 = blockIdx.x * 64 + wave * 16;
  int lw = wave * 16;

  // fold 8-replica BN stats -> affine coefs
  if (tid < 128) {
    float s = 0.f, s2 = 0.f, t = 0.f, t2 = 0.f;
    #pragma unroll
    for (int rr = 0; rr < 8; rr++) {
      s  += st1[rr * 256 + tid];  s2 += st1[rr * 256 + 128 + tid];
      t  += st2[rr * 256 + tid];  t2 += st2[rr * 256 + 128 + tid];
    }
    float mu  = s * (1.f / 32768.f);
    float var = fmaxf(s2 * (1.f / 32768.f) - mu * mu, 0.f);
    float k = rsqrtf(var + EPSV) * bf2f(bw1[tid]);
    kc1[tid] = k; oc1[tid] = bf2f(bb1[tid]) - mu * k;
    mu  = t * (1.f / 32768.f);
    var = fmaxf(t2 * (1.f / 32768.f) - mu * mu, 0.f);
    k = rsqrtf(var + EPSV) * bf2f(bw2[tid]);
    kc2[tid] = k; oc2[tid] = bf2f(bb2[tid]) - mu * k;
  }
  __syncthreads();

  // A fragments = comb(row0+l16, :) computed from F1a/F1b
  bf16x8 a[4];
  {
    int arow = row0 + l16;
    const float* pa = F1a + (size_t)arow * 128;
    const float* pb = F1b + (size_t)arow * 128;
    #pragma unroll
    for (int kk = 0; kk < 4; kk++) {
      int c0 = kk * 32 + quad * 8;
      float4 xa0 = *(const float4*)(pa + c0);
      float4 xa1 = *(const float4*)(pa + c0 + 4);
      float4 xb0 = *(const float4*)(pb + c0);
      float4 xb1 = *(const float4*)(pb + c0 + 4);
      float xa[8] = {xa0.x, xa0.y, xa0.z, xa0.w, xa1.x, xa1.y, xa1.z, xa1.w};
      float xb[8] = {xb0.x, xb0.y, xb0.z, xb0.w, xb1.x, xb1.y, xb1.z, xb1.w};
      bf16x8 frag;
      #pragma unroll
      for (int j = 0; j < 8; j++) {
        int c = c0 + j;
        float h1v = bf2f(f2bf(sane(xa[j]) * kc1[c] + oc1[c]));
        frag[j] = (short)f2bf(sane(xb[j]) * kc2[c] + oc2[c] + h1v);
      }
      a[kk] = frag;
    }
  }

  for (int seg = 0; seg < 2; seg++) {
    if (seg) __syncthreads();
    for (int i = tid; i < 2048; i += 256) {
      int col = i >> 4, ko = (i & 15) * 8;
      *(bf16x8*)&Bs[col * BP + ko] =
          *(const bf16x8*)(W1 + (size_t)(seg * 128 + col) * 128 + ko);
    }
    __syncthreads();
    f32x4 acc[8];
    #pragma unroll
    for (int nt = 0; nt < 8; nt++) acc[nt] = (f32x4){0.f, 0.f, 0.f, 0.f};
    #pragma unroll
    for (int kk = 0; kk < 4; kk++)
      #pragma unroll
      for (int nt = 0; nt < 8; nt++) {
        bf16x8 b = *(const bf16x8*)(&Bs[(nt * 16 + l16) * BP + kk * 32 + quad * 8]);
        acc[nt] = __builtin_amdgcn_mfma_f32_16x16x32_bf16(a[kk], b, acc[nt], 0, 0, 0);
      }
    #pragma unroll
    for (int nt = 0; nt < 8; nt++) {
      int col = seg * 128 + nt * 16 + l16;
      float bv = bf2f(B1[col]);
      #pragma unroll
      for (int r = 0; r < 4; r++)
        Hs[(lw + quad * 4 + r) * HP + col] = f2bf(fmaxf(acc[nt][r] + bv, 0.f));
    }
  }
  __syncthreads();
  if (tid < 256) ls[tid] = 0.f;

  f32x4 acc2[8];
  #pragma unroll
  for (int nt = 0; nt < 8; nt++) acc2[nt] = (f32x4){0.f, 0.f, 0.f, 0.f};
  for (int kc = 0; kc < 2; kc++) {
    if (kc) __syncthreads();
    for (int i = tid; i < 2048; i += 256) {
      int col = i >> 4, ko = (i & 15) * 8;
      *(bf16x8*)&Bs[col * BP + ko] =
          *(const bf16x8*)(W2 + (size_t)col * 256 + kc * 128 + ko);
    }
    bf16x8 a2[4];
    #pragma unroll
    for (int kk = 0; kk < 4; kk++)
      a2[kk] = *(const bf16x8*)(&Hs[(lw + l16) * HP + kc * 128 + kk * 32 + quad * 8]);
    __syncthreads();
    #pragma unroll
    for (int kk = 0; kk < 4; kk++)
      #pragma unroll
      for (int nt = 0; nt < 8; nt++) {
        bf16x8 b = *(const bf16x8*)(&Bs[(nt * 16 + l16) * BP + kk * 32 + quad * 8]);
        acc2[nt] = __builtin_amdgcn_mfma_f32_16x16x32_bf16(a2[kk], b, acc2[nt], 0, 0, 0);
      }
  }

  #pragma unroll
  for (int nt = 0; nt < 8; nt++) {
    int col = nt * 16 + l16;
    float bv = bf2f(B2[col]);
    float cs_ = 0.f, cs2 = 0.f;
    #pragma unroll
    for (int r = 0; r < 4; r++) {
      int row = row0 + quad * 4 + r;
      // recompute comb residual (identical rounding to A fragments)
      float xa = sane(F1a[(size_t)row * 128 + col]);
      float xb = sane(F1b[(size_t)row * 128 + col]);
      float h1v = bf2f(f2bf(xa * kc1[col] + oc1[col]));
      ushort cb = f2bf(xb * kc2[col] + oc2[col] + h1v);
      float v = acc2[nt][r] + bv + bf2f(cb);
      outp[(size_t)row * 128 + col] = v;
      float sv = sane(v); cs_ += sv; cs2 += sv * sv;
    }
    atomicAdd(&ls[col], cs_); atomicAdd(&ls[128 + col], cs2);
  }
  __syncthreads();
  float* gs = gstats + (blockIdx.x & 7) * 256;
  if (tid < 128) {
    atomicAdd(&gs[tid], ls[tid]);
    atomicAdd(&gs[128 + tid], ls[128 + tid]);
  }
}

// ---------------- fused lhat / Chebyshev recurrence (4-wide gather) --------
__global__ __launch_bounds__(256) void spmm_cheb(
    const int* __restrict__ row_ptr, const int2* __restrict__ ep,
    const ushort* __restrict__ v,
    const ushort* __restrict__ txprev, ushort* __restrict__ txout,
    const ushort* __restrict__ lambda_max, int first, int str)
{
  int wave = threadIdx.x >> 6, lane = threadIdx.x & 63;
  int sub = lane >> 4, l16 = lane & 15;
  int d = blockIdx.x * 4 + wave;
  float lm = bf2f(lambda_max[0]);
  float scale = 2.f / lm;
  if (!(scale == scale) || fabsf(scale) > 1e6f) scale = 1.f;
  int beg = row_ptr[d];
  int end = (d == N - 1) ? E : row_ptr[d + 1];
  float acc[8] = {0.f,0.f,0.f,0.f,0.f,0.f,0.f,0.f};
  for (int jb = beg; jb < end; jb += 16) {
    int j0 = jb + sub, j1 = jb + 4 + sub, j2 = jb + 8 + sub, j3 = jb + 12 + sub;
    int2 e0 = ep[j0 < end ? j0 : 0];
    int2 e1 = ep[j1 < end ? j1 : 0];
    int2 e2 = ep[j2 < end ? j2 : 0];
    int2 e3 = ep[j3 < end ? j3 : 0];
    bf16x8 v0 = *(const bf16x8*)(v + (size_t)(e0.x & (N - 1)) * str + l16 * 8);
    bf16x8 v1 = *(const bf16x8*)(v + (size_t)(e1.x & (N - 1)) * str + l16 * 8);
    bf16x8 v2 = *(const bf16x8*)(v + (size_t)(e2.x & (N - 1)) * str + l16 * 8);
    bf16x8 v3 = *(const bf16x8*)(v + (size_t)(e3.x & (N - 1)) * str + l16 * 8);
    float w0 = j0 < end ? __int_as_float(e0.y) : 0.f;
    float w1 = j1 < end ? __int_as_float(e1.y) : 0.f;
    float w2 = j2 < end ? __int_as_float(e2.y) : 0.f;
    float w3 = j3 < end ? __int_as_float(e3.y) : 0.f;
    #pragma unroll
    for (int i = 0; i < 8; i++) acc[i] += w0 * bf2f((ushort)v0[i]);
    #pragma unroll
    for (int i = 0; i < 8; i++) acc[i] += w1 * bf2f((ushort)v1[i]);
    #pragma unroll
    for (int i = 0; i < 8; i++) acc[i] += w2 * bf2f((ushort)v2[i]);
    #pragma unroll
    for (int i = 0; i < 8; i++) acc[i] += w3 * bf2f((ushort)v3[i]);
  }
  #pragma unroll
  for (int i = 0; i < 8; i++) {
    acc[i] += __shfl_xor(acc[i], 16);
    acc[i] += __shfl_xor(acc[i], 32);
  }
  if (sub == 0) {
    bf16x8 vd = *(const bf16x8*)(v + (size_t)d * str + l16 * 8);
    bf16x8 tp;
    if (!first) tp = *(const bf16x8*)(txprev + (size_t)d * str + l16 * 8);
    bf16x8 ov;
    #pragma unroll
    for (int i = 0; i < 8; i++) {
      float r = (scale - 1.f) * bf2f((ushort)vd[i]) - scale * acc[i];
      if (!first) r = 2.f * r - bf2f((ushort)tp[i]);
      ov[i] = (short)f2bf(r);
    }
    *(bf16x8*)(txout + (size_t)d * str + l16 * 8) = ov;
  }
}

// ---------------- U^T @ h_proj partials via MFMA (256 blocks, full GPU) ----
__global__ __launch_bounds__(256) void ut_mfma(const ushort* __restrict__ U,
    const ushort* __restrict__ hp, float* __restrict__ parts)
{
  constexpr int RP = 40;
  __shared__ ushort Ut[128 * RP];
  __shared__ ushort Ht[128 * RP];
  int t = threadIdx.x;
  int lane = t & 63, wave = t >> 6;
  int quad = lane >> 4, l16 = lane & 15;

  f32x4 acc[2][8];
  #pragma unroll
  for (int a = 0; a < 2; a++)
    #pragma unroll
    for (int ct = 0; ct < 8; ct++) acc[a][ct] = (f32x4){0.f, 0.f, 0.f, 0.f};

  for (int ch = 0; ch < 4; ch++) {
    int n0 = blockIdx.x * 128 + ch * 32;
    __syncthreads();
    for (int i = t; i < 2048; i += 256) {
      int r2 = i >> 7, c = i & 127;
      uint u0 = U [(size_t)(n0 + r2 * 2) * 128 + c];
      uint u1 = U [(size_t)(n0 + r2 * 2 + 1) * 128 + c];
      *(uint*)&Ut[c * RP + r2 * 2] = (u0 & 0xffffu) | (u1 << 16);
      uint h0 = hp[(size_t)(n0 + r2 * 2) * 128 + c];
      uint h1 = hp[(size_t)(n0 + r2 * 2 + 1) * 128 + c];
      *(uint*)&Ht[c * RP + r2 * 2] = (h0 & 0xffffu) | (h1 << 16);
    }
    __syncthreads();
    bf16x8 bfr[8];
    #pragma unroll
    for (int ct = 0; ct < 8; ct++)
      bfr[ct] = *(const bf16x8*)(&Ht[(ct * 16 + l16) * RP + quad * 8]);
    #pragma unroll
    for (int a = 0; a < 2; a++) {
      int kt = wave * 2 + a;
      bf16x8 af = *(const bf16x8*)(&Ut[(kt * 16 + l16) * RP + quad * 8]);
      #pragma unroll
      for (int ct = 0; ct < 8; ct++)
        acc[a][ct] = __builtin_amdgcn_mfma_f32_16x16x32_bf16(af, bfr[ct], acc[a][ct], 0, 0, 0);
    }
  }

  float* po = parts + (size_t)blockIdx.x * 16384;
  #pragma unroll
  for (int a = 0; a < 2; a++) {
    int kt = wave * 2 + a;
    #pragma unroll
    for (int ct = 0; ct < 8; ct++)
      #pragma unroll
      for (int r = 0; r < 4; r++)
        po[(kt * 16 + quad * 4 + r) * 128 + ct * 16 + l16] = acc[a][ct][r];
  }
}

__global__ __launch_bounds__(256) void reduce_mt(const float* __restrict__ parts,
    const ushort* __restrict__ Lambda, const ushort* __restrict__ gamma,
    ushort* __restrict__ MT)
{
  int e = blockIdx.x * 256 + threadIdx.x;
  int keig = e >> 7, c = e & 127;
  float s = 0.f;
  for (int p = 0; p < UT_BLOCKS; p++) s += parts[(size_t)p * 16384 + e];
  float g = bf2f(gamma[0]);
  float lam = bf2f(Lambda[keig]);
  float sl = __expf(-g * lam * lam);
  MT[c * 128 + keig] = f2bf(sl * s);
}

// ---------------- BatchNorm apply (stats from 8 replicated bins) ----------
__global__ __launch_bounds__(256) void bn_apply(const float* __restrict__ h,
    const float* __restrict__ st, const ushort* __restrict__ gw,
    const ushort* __restrict__ gb, const ushort* __restrict__ add,
    void* __restrict__ out, const uint* __restrict__ lmraw, int final_out)
{
  __shared__ float sk[128], sb[128];
  int tid = threadIdx.x;
  if (tid < 128) {
    float s = 0.f, s2 = 0.f;
    #pragma unroll
    for (int rr = 0; rr < 8; rr++) {
      s  += st[rr * 256 + tid];
      s2 += st[rr * 256 + 128 + tid];
    }
    float mu  = s * (1.f / 32768.f);
    float var = fmaxf(s2 * (1.f / 32768.f) - mu * mu, 0.f);
    float k = rsqrtf(var + EPSV) * bf2f(gw[tid]);
    sk[tid] = k;
    sb[tid] = bf2f(gb[tid]) - mu * k;
  }
  __syncthreads();
  size_t e = ((size_t)blockIdx.x * 256 + tid) * 4;
  int c0 = (int)(e & 127);
  float4 hv = *(const float4*)(h + e);
  float xv[4] = {sane(hv.x), sane(hv.y), sane(hv.z), sane(hv.w)};
  float addv[4] = {0.f, 0.f, 0.f, 0.f};
  if (add) {
    ushort4 av = *(const ushort4*)(add + e);
    addv[0] = bf2f(av.x); addv[1] = bf2f(av.y);
    addv[2] = bf2f(av.z); addv[3] = bf2f(av.w);
  }
  float r[4];
  #pragma unroll
  for (int j = 0; j < 4; j++) {
    int c = c0 + j;
    r[j] = xv[j] * sk[c] + sb[c] + addv[j];
  }
  if (final_out && mode_fp32(lmraw)) {
    float4 o4; o4.x = r[0]; o4.y = r[1]; o4.z = r[2]; o4.w = r[3];
    *(float4*)((float*)out + e) = o4;
  } else {
    ushort4 o;
    o.x = f2bf(r[0]); o.y = f2bf(r[1]); o.z = f2bf(r[2]); o.w = f2bf(r[3]);
    *(ushort4*)((ushort*)out + e) = o;
  }
}

// ---------------- MFMA flash attention ----------------
__global__ __launch_bounds__(512) void attn_mfma(const ushort* __restrict__ qkv,
                                                 ushort* __restrict__ attn)
{
  constexpr int VP = 516;            // 258 words = 2 mod 32
  constexpr int KP = 40;             // 20 words -> 2-way max on b128 (free)
  __shared__ ushort Kt[512 * KP];    // 40 KB  [key][dim]
  __shared__ ushort Vt[32 * VP];     // 33 KB  [dim][key]
  int b = blockIdx.x;
  int g = b >> 3, hh = (b >> 1) & 3, half = b & 1;
  int lane = threadIdx.x & 63, wave = threadIdx.x >> 6;   // wave 0..7
  int quad = lane >> 4, l16 = lane & 15;
  const ushort* base = qkv + (size_t)g * 512 * 384;

  for (int i = threadIdx.x; i < 512 * 4; i += 512) {
    int key = i >> 2, c8 = (i & 3) * 8;
    *(bf16x8*)&Kt[key * KP + c8] =
        *(const bf16x8*)(base + (size_t)key * 384 + 128 + hh * 32 + c8);
  }
  for (int i = threadIdx.x; i < 256 * 8; i += 512) {
    int kp = i >> 3, d4 = (i & 7) * 4;
    const ushort* va = base + (size_t)(2 * kp) * 384 + 256 + hh * 32 + d4;
    ushort4 a = *(const ushort4*)va;
    ushort4 c = *(const ushort4*)(va + 384);
    *(uint*)&Vt[(d4 + 0) * VP + 2 * kp] = (uint)a.x | ((uint)c.x << 16);
    *(uint*)&Vt[(d4 + 1) * VP + 2 * kp] = (uint)a.y | ((uint)c.y << 16);
    *(uint*)&Vt[(d4 + 2) * VP + 2 * kp] = (uint)a.z | ((uint)c.z << 16);
    *(uint*)&Vt[(d4 + 3) * VP + 2 * kp] = (uint)a.w | ((uint)c.w << 16);
  }
  __syncthreads();

  int q0 = half * 256 + wave * 32;
  bf16x8 qf[2];
  #pragma unroll
  for (int i = 0; i < 2; i++)
    qf[i] = *(const bf16x8*)(base + (size_t)(q0 + i * 16 + l16) * 384 + hh * 32 + quad * 8);

  f32x4 O[2][2];
  #pragma unroll
  for (int dt = 0; dt < 2; dt++)
    #pragma unroll
    for (int i = 0; i < 2; i++) O[dt][i] = (f32x4){0.f, 0.f, 0.f, 0.f};
  float lsum[2] = {0.f, 0.f};

  union PU { uint u[4]; bf16x8 v; };
  union VU { uint2 a[2]; bf16x8 v; };

  for (int kt2 = 0; kt2 < 16; kt2++) {
    int k0 = kt2 * 32;
    bf16x8 kfA = *(const bf16x8*)&Kt[(k0 + l16) * KP + quad * 8];
    bf16x8 kfB = *(const bf16x8*)&Kt[(k0 + 16 + l16) * KP + quad * 8];
    PU pw[2];
    #pragma unroll
    for (int i = 0; i < 2; i++) {
      f32x4 sA = __builtin_amdgcn_mfma_f32_16x16x32_bf16(kfA, qf[i], (f32x4){0.f,0.f,0.f,0.f}, 0, 0, 0);
      f32x4 sB = __builtin_amdgcn_mfma_f32_16x16x32_bf16(kfB, qf[i], (f32x4){0.f,0.f,0.f,0.f}, 0, 0, 0);
      float p0 = fexp2(fminf(sA[0], 86.5f));
      float p1 = fexp2(fminf(sA[1], 86.5f));
      float p2 = fexp2(fminf(sA[2], 86.5f));
      float p3 = fexp2(fminf(sA[3], 86.5f));
      float p4 = fexp2(fminf(sB[0], 86.5f));
      float p5 = fexp2(fminf(sB[1], 86.5f));
      float p6 = fexp2(fminf(sB[2], 86.5f));
      float p7 = fexp2(fminf(sB[3], 86.5f));
      lsum[i] += ((p0 + p1) + (p2 + p3)) + ((p4 + p5) + (p6 + p7));
      pw[i].u[0] = cvtpk(p0, p1); pw[i].u[1] = cvtpk(p2, p3);
      pw[i].u[2] = cvtpk(p4, p5); pw[i].u[3] = cvtpk(p6, p7);
    }
    #pragma unroll
    for (int dt = 0; dt < 2; dt++) {
      int drow = (dt * 16 + l16) * VP;
      VU vu;
      vu.a[0] = *(const uint2*)&Vt[drow + k0 + quad * 4];
      vu.a[1] = *(const uint2*)&Vt[drow + k0 + 16 + quad * 4];
      #pragma unroll
      for (int i = 0; i < 2; i++)
        O[dt][i] = __builtin_amdgcn_mfma_f32_16x16x32_bf16(vu.v, pw[i].v, O[dt][i], 0, 0, 0);
    }
  }

  #pragma unroll
  for (int i = 0; i < 2; i++) {
    float l = lsum[i];
    l += __shfl_xor(l, 16);
    l += __shfl_xor(l, 32);
    lsum[i] = 1.f / l;
  }

  #pragma unroll
  for (int i = 0; i < 2; i++) {
    size_t node = (size_t)g * 512 + q0 + i * 16 + l16;
    #pragma unroll
    for (int dt = 0; dt < 2; dt++) {
      uint2 o;
      o.x = cvtpk(O[dt][i][0] * lsum[i], O[dt][i][1] * lsum[i]);
      o.y = cvtpk(O[dt][i][2] * lsum[i], O[dt][i][3] * lsum[i]);
      *(uint2*)(attn + node * 128 + hh * 32 + dt * 16 + quad * 4) = o;
    }
  }
}

// ---------------- workspace layout (bytes), total 103 MB ----------------
constexpr size_t KB = 1024;
constexpr size_t MB = 1048576;
constexpr size_t OFF_WT    = 0;                 // 576 KB
constexpr size_t OFF_CDT   = 576 * KB;          // 128 KB (cnt_dst totals)
constexpr size_t OFF_RP    = 704 * KB;          // 128 KB
constexpr size_t OFF_DIS   = 832 * KB;          // 128 KB
constexpr size_t OFF_MT    = 960 * KB;          // 32 KB
constexpr size_t OFF_STATS = 1024 * KB;         // 24 KB (3 BN x 8 reps x 256 f32) [zeroed]
constexpr size_t OFF_CEI   = 6  * MB;           // 4 MB
constexpr size_t OFF_EP    = 10 * MB;           // 4 MB (packed int2 per slot)
constexpr size_t OFF_CANX  = 14 * MB;           // 8 MB
constexpr size_t OFF_CANU  = 22 * MB;           // 8 MB
constexpr size_t OFF_CANS  = 30 * MB;           // ~0.6 MB
constexpr size_t OFF_F1    = 31 * MB;           // fp32 16 MB (F1a)
constexpr size_t OFF_HPROJ = 39 * MB;           // 8 MB (dead before F1a write)
constexpr size_t OFF_TBIG  = 47 * MB;           // 40 MB cheb T; later qkvb+F1B
constexpr size_t OFF_PARTH = OFF_TBIG;          // 16 MB hist partials
constexpr size_t OFF_OFF2  = OFF_TBIG + 16 * MB;// 16 MB per-block slot bases
constexpr size_t OFF_F1B   = 71 * MB;           // fp32 16 MB (Tbig tail)
constexpr size_t OFF_PARTS = 87 * MB;           // 16 MB; attnb shares; end 103 MB

extern "C" void kernel_launch(void* const* d_in, const int* in_sizes, int n_in,
                              void* d_out, int out_size, void* d_ws, size_t ws_size,
                              hipStream_t stream) {
  (void)in_sizes; (void)n_in; (void)out_size; (void)ws_size;
  const uint* lmraw = (const uint*)d_in[3];
  const int*  ei    = (const int*)d_in[30];

  char* W = (char*)d_ws;
  ushort* wt    = (ushort*)(W + OFF_WT);
  int*    cdt   = (int*)(W + OFF_CDT);
  int*    rp    = (int*)(W + OFF_RP);
  float*  dis   = (float*)(W + OFF_DIS);
  ushort* MT    = (ushort*)(W + OFF_MT);
  float*  stats = (float*)(W + OFF_STATS);
  int*    cei   = (int*)(W + OFF_CEI);
  int2*   ep    = (int2*)(W + OFF_EP);
  ushort* part  = (ushort*)(W + OFF_PARTH);
  int*    off2  = (int*)(W + OFF_OFF2);
  ushort* canx  = (ushort*)(W + OFF_CANX);
  ushort* canu  = (ushort*)(W + OFF_CANU);
  ushort* cs    = (ushort*)(W + OFF_CANS);
  float*  F1    = (float*)(W + OFF_F1);
  float*  F1B   = (float*)(W + OFF_F1B);
  ushort* hproj = (ushort*)(W + OFF_HPROJ);
  ushort* Tbig  = (ushort*)(W + OFF_TBIG);
  ushort* qkvb  = (ushort*)(W + OFF_TBIG);
  float*  parts = (float*)(W + OFF_PARTS);
  ushort* attnb = (ushort*)(W + OFF_PARTS);

  const ushort* cLambda = cs + COF[0];
  const ushort* cLmx    = cs + COF[1];
  const ushort* cBspa1  = cs + COF[3];
  const ushort* cBspa2  = cs + COF[5];
  const ushort* cBspe1  = cs + COF[7];
  const ushort* cBspe2  = cs + COF[9];
  const ushort* cChebB  = cs + COF[11];
  const ushort* cGam    = cs + COF[12];
  const ushort* cBqkv   = cs + COF[15];
  const ushort* cBout   = cs + COF[17];
  const ushort* cMb1    = cs + COF[19];
  const ushort* cMb2    = cs + COF[21];
  const ushort* cBn1w   = cs + COF[22];
  const ushort* cBn1b   = cs + COF[23];
  const ushort* cBn2w   = cs + COF[24];
  const ushort* cBn2b   = cs + COF[25];
  const ushort* cBn3w   = cs + COF[26];
  const ushort* cBn3b   = cs + COF[27];

  const ushort* NUL = nullptr;
  float* NULF = nullptr;
  (void)NUL; (void)NULF;

  // ---- fused canonicalize + transpose + zero ----
  CvtArgs ca;
  ca.src[0]  = d_in[2];  ca.src[1]  = d_in[3];  ca.src[2]  = d_in[4];
  ca.src[3]  = d_in[5];  ca.src[4]  = d_in[6];  ca.src[5]  = d_in[7];
  ca.src[6]  = d_in[8];  ca.src[7]  = d_in[9];  ca.src[8]  = d_in[10];
  ca.src[9]  = d_in[11]; ca.src[10] = d_in[12]; ca.src[11] = d_in[13];
  ca.src[12] = d_in[14]; ca.src[13] = d_in[15]; ca.src[14] = d_in[16];
  ca.src[15] = d_in[17]; ca.src[16] = d_in[18]; ca.src[17] = d_in[19];
  ca.src[18] = d_in[20]; ca.src[19] = d_in[21]; ca.src[20] = d_in[22];
  ca.src[21] = d_in[23]; ca.src[22] = d_in[24]; ca.src[23] = d_in[25];
  ca.src[24] = d_in[26]; ca.src[25] = d_in[27]; ca.src[26] = d_in[28];
  ca.src[27] = d_in[29];
  prep_all<<<10530, 256, 0, stream>>>(ca, d_in[0], d_in[1], canx, canu, cs, wt,
                                      (int*)(W + OFF_STATS), lmraw);

  // ---- edge prep (LDS-private histograms, no device-scope atomics) ----
  hist_lds<<<2 * HB, 1024, 0, stream>>>(ei, cei, part);
  reduce_cnt<<<N / 256, 256, 0, stream>>>(part, cdt, dis);
  scan_kernel<<<1, 1024, 0, stream>>>(cdt, rp);
  off_kernel<<<N / 256, 256, 0, stream>>>(rp, part, off2);
  edge_scatter<<<HB, 1024, 0, stream>>>(cei, off2, dis, ep);

  dim3 g1(512), bb(256);
  // ---- merged spa+spe input MLP chains (one canx read, reg-prefetched) ----
  gemm_chain2<<<g1, bb, 0, stream>>>(canx,
      wt + WT_SPA1, cBspa1, wt + WT_SPA2, cBspa2,
      wt + WT_SPE1, cBspe1, wt + WT_SPE2, cBspe2,
      wt + WT_PROJ, Tbig, hproj);

  // ---- spectral filter M^T ----
  ut_mfma<<<UT_BLOCKS, 256, 0, stream>>>(canu, hproj, parts);
  reduce_mt<<<64, 256, 0, stream>>>(parts, cLambda, cGam, MT);

  // ---- Chebyshev recurrence into Tbig ----
  spmm_cheb<<<N / 4, 256, 0, stream>>>(rp, ep, Tbig,       NUL,        Tbig + 128, cLmx, 1, 640);
  spmm_cheb<<<N / 4, 256, 0, stream>>>(rp, ep, Tbig + 128, Tbig,       Tbig + 256, cLmx, 0, 640);
  spmm_cheb<<<N / 4, 256, 0, stream>>>(rp, ep, Tbig + 256, Tbig + 128, Tbig + 384, cLmx, 0, 640);
  spmm_cheb<<<N / 4, 256, 0, stream>>>(rp, ep, Tbig + 384, Tbig + 256, Tbig + 512, cLmx, 0, 640);

  // ---- fused cheb GEMM + spectral MT GEMM + x residual + BN1 stats -> F1a ----
  gemm_cheb_mt<<<g1, bb, 0, stream>>>(Tbig, wt + WT_CHEB, cChebB, canu, MT, canx,
                                      F1, stats);

  // ---- attention branch (Q pre-scaled in QKV epilogue; one A-read) ----
  gemm_qkv<<<g1, bb, 0, stream>>>(canx, wt + WT_QKV, cBqkv, qkvb);
  attn_mfma<<<512, 512, 0, stream>>>(qkvb, attnb);
  gemm_lds<128,128,false,1,true ,true ,128,128,false,true ><<<g1, bb, 0, stream>>>(attnb, wt + WT_WOUT, cBout, canx, F1B, stats + 2048);

  // ---- fused MLP (BN1+BN2 combine in-kernel, +BN3 stats) + final BN ----
  gemm_mlp<<<g1, bb, 0, stream>>>(F1, F1B, stats, stats + 2048,
      cBn1w, cBn1b, cBn2w, cBn2b,
      wt + WT_MLP1, cMb1, wt + WT_MLP2, cMb2, F1, stats + 4096);
  bn_apply<<<(N * C) / 1024, 256, 0, stream>>>(F1, stats + 4096, cBn3w, cBn3b, NUL, d_out, lmraw, 1);
}